// Round 2
// baseline (4543.132 us; speedup 1.0000x reference)
//
#include <hip/hip_runtime.h>
#include <hip/hip_fp16.h>

#define N_NODES 1000000
#define N_EDGES 4000000
#define N_GRAPHS 32768
#define BN_EPS 1e-5f
#define NBLK1 3907   // ceil(N_NODES/256)

typedef _Float16 f16;
typedef f16   f16x8 __attribute__((ext_vector_type(8)));
typedef float f32x4 __attribute__((ext_vector_type(4)));

// ---------------------------------------------------------------------------
// Static device-global scratch (ws_size too small for the intermediates).
// fp16 ping-pong feature buffers keep the edge-gather set L3-resident.
// NOTE: device globals must ONLY be referenced from device code (round-6
// fault: host-side refs pass the host shadow address). Buffer selection is
// via template parameters.
// ---------------------------------------------------------------------------
__device__ __half g_hA[128000000];      // 256 MB node features
__device__ __half g_hB[128000000];      // 256 MB node features (aliased as f32 px in layer 1)
__device__ float  g_agg7[8400000];      //  33.6 MB layer-1 agg (8 floats/node, padded); later pooled+hidden
__device__ float  g_dinv[N_NODES];
__device__ int    g_rowcnt[N_NODES];
__device__ int    g_row_start[N_NODES + 1];
__device__ int    g_csr_src[N_EDGES];
__device__ int    g_part[NBLK1];
__device__ int    g_gstart[N_GRAPHS + 1];
__device__ __align__(16) __half g_wt2[16384];   // W2^T fp16 [n][k]
__device__ __align__(16) __half g_wt3[16384];   // W3^T fp16 [n][k]

#define HIDDEN_OFF 4259840   // pooled = g_agg7[0..4194304); hidden after pad

// ---------------- fp16 helpers (16 B = 8 halfs per lane) ----------------

__device__ __forceinline__ void set8(uint4 raw, float f[8]) {
    __half2 h; float2 a;
    __builtin_memcpy(&h, &raw.x, 4); a = __half22float2(h); f[0] = a.x; f[1] = a.y;
    __builtin_memcpy(&h, &raw.y, 4); a = __half22float2(h); f[2] = a.x; f[3] = a.y;
    __builtin_memcpy(&h, &raw.z, 4); a = __half22float2(h); f[4] = a.x; f[5] = a.y;
    __builtin_memcpy(&h, &raw.w, 4); a = __half22float2(h); f[6] = a.x; f[7] = a.y;
}
__device__ __forceinline__ void add8(uint4 raw, float f[8]) {
    __half2 h; float2 a;
    __builtin_memcpy(&h, &raw.x, 4); a = __half22float2(h); f[0] += a.x; f[1] += a.y;
    __builtin_memcpy(&h, &raw.y, 4); a = __half22float2(h); f[2] += a.x; f[3] += a.y;
    __builtin_memcpy(&h, &raw.z, 4); a = __half22float2(h); f[4] += a.x; f[5] += a.y;
    __builtin_memcpy(&h, &raw.w, 4); a = __half22float2(h); f[6] += a.x; f[7] += a.y;
}
__device__ __forceinline__ uint4 pack8(const float f[8]) {
    __half2 h0 = __floats2half2_rn(f[0], f[1]);
    __half2 h1 = __floats2half2_rn(f[2], f[3]);
    __half2 h2 = __floats2half2_rn(f[4], f[5]);
    __half2 h3 = __floats2half2_rn(f[6], f[7]);
    uint4 raw;
    __builtin_memcpy(&raw.x, &h0, 4);
    __builtin_memcpy(&raw.y, &h1, 4);
    __builtin_memcpy(&raw.z, &h2, 4);
    __builtin_memcpy(&raw.w, &h3, 4);
    return raw;
}

// ---------------- CSR build ----------------

__global__ __launch_bounds__(256) void k_zero_cnt() {
    int i = blockIdx.x * 256 + threadIdx.x;
    if (i < N_NODES) g_rowcnt[i] = 0;
}

__global__ __launch_bounds__(256) void k_hist(const int* __restrict__ dst) {
    int e = blockIdx.x * 256 + threadIdx.x;
    if (e < N_EDGES) atomicAdd(&g_rowcnt[dst[e]], 1);
}

// scan1 also computes dinv (reads rowcnt anyway) — saves a launch
__global__ __launch_bounds__(256) void k_scan1() {
    __shared__ int sh[256];
    int i = blockIdx.x * 256 + threadIdx.x;
    int v = (i < N_NODES) ? g_rowcnt[i] : 0;
    if (i < N_NODES) g_dinv[i] = rsqrtf((float)(1 + v));   // +1 self-loop
    sh[threadIdx.x] = v;
    __syncthreads();
#pragma unroll
    for (int off = 1; off < 256; off <<= 1) {
        int t = (threadIdx.x >= off) ? sh[threadIdx.x - off] : 0;
        __syncthreads();
        sh[threadIdx.x] += t;
        __syncthreads();
    }
    int incl = sh[threadIdx.x];
    if (i < N_NODES) g_row_start[i] = incl - v;
    if (threadIdx.x == 255) g_part[blockIdx.x] = incl;
}

__global__ __launch_bounds__(256) void k_scan2() {
    __shared__ int sh[256];
    int base = threadIdx.x * 16;
    int local[16];
    int s = 0;
#pragma unroll
    for (int k = 0; k < 16; ++k) {
        local[k] = (base + k < NBLK1) ? g_part[base + k] : 0;
        s += local[k];
    }
    sh[threadIdx.x] = s;
    __syncthreads();
#pragma unroll
    for (int off = 1; off < 256; off <<= 1) {
        int t = (threadIdx.x >= off) ? sh[threadIdx.x - off] : 0;
        __syncthreads();
        sh[threadIdx.x] += t;
        __syncthreads();
    }
    int carry = sh[threadIdx.x] - s;
#pragma unroll
    for (int k = 0; k < 16; ++k) {
        if (base + k < NBLK1) {
            int t = local[k];
            g_part[base + k] = carry;
            carry += t;
        }
    }
}

__global__ __launch_bounds__(256) void k_scan3() {
    int i = blockIdx.x * 256 + threadIdx.x;
    if (i < N_NODES) {
        g_row_start[i] += g_part[blockIdx.x];
        g_rowcnt[i] = 0;
    }
    if (i == 0) g_row_start[N_NODES] = N_EDGES;
}

__global__ __launch_bounds__(256) void k_scatter(const int* __restrict__ src,
                                                 const int* __restrict__ dst) {
    int e = blockIdx.x * 256 + threadIdx.x;
    if (e >= N_EDGES) return;
    int d = dst[e];
    int pos = g_row_start[d] + atomicAdd(&g_rowcnt[d], 1);
    g_csr_src[pos] = src[e];
}

// ---------------- W2+W3 transpose to fp16 (single launch) ----------------
// Wt[n][k] = (fp16) W[k][n]. Blocks 0..63 -> W2, 64..127 -> W3.

__global__ __launch_bounds__(256) void k_wt_both(const float* __restrict__ W2,
                                                 const float* __restrict__ W3) {
    int t = blockIdx.x * 256 + threadIdx.x;   // 0..32767
    int sel = t >> 14, u = t & 16383;
    int n = u & 127, k = u >> 7;
    __half* dst = sel ? g_wt3 : g_wt2;
    const float* W = sel ? W3 : W2;
    dst[n * 128 + k] = __float2half_rn(W[k * 128 + n]);
}

// ---------------- layer 1 ----------------

// px[i] = dinv[i]*x[i]  (px aliases g_hB as f32; dead once layer 2 runs)
__global__ __launch_bounds__(256) void k_p7(const float* __restrict__ x) {
    int i = blockIdx.x * 256 + threadIdx.x;
    if (i >= N_NODES) return;
    float w = g_dinv[i];
    float* px = (float*)g_hB;
#pragma unroll
    for (int k = 0; k < 7; ++k) px[i * 7 + k] = x[i * 7 + k] * w;
}

// agg7[d] = px[d] + sum px[s], 8 lanes/node, 4-deep MLP.
// Stored PADDED to 8 floats/node (c==7 writes 0) so lin1 loads aligned float4s.
__global__ __launch_bounds__(256) void k_agg7_csr() {
    int t = blockIdx.x * 256 + threadIdx.x;
    int i = t >> 3;
    int c = t & 7;
    if (i >= N_NODES) return;
    if (c == 7) { g_agg7[(size_t)i * 8 + 7] = 0.f; return; }
    const float* px = (const float*)g_hB;
    float acc = px[i * 7 + c];
    int e = g_row_start[i], e1 = g_row_start[i + 1];
    for (; e + 4 <= e1; e += 4) {
        int s0 = g_csr_src[e + 0], s1 = g_csr_src[e + 1];
        int s2 = g_csr_src[e + 2], s3 = g_csr_src[e + 3];
        float v0 = px[s0 * 7 + c], v1 = px[s1 * 7 + c];
        float v2 = px[s2 * 7 + c], v3 = px[s3 * 7 + c];
        acc += (v0 + v1) + (v2 + v3);
    }
    for (; e < e1; ++e) acc += px[g_csr_src[e] * 7 + c];
    g_agg7[(size_t)i * 8 + c] = acc;
}

// h1 = relu(bn(dinv*(agg7.W1) + b)); store q1 = dinv*h1 (fp16).
// 16 threads/node x 8 ch, aligned 2xfloat4 agg7 loads, W1+BN params staged
// in LDS, one uint4 fp16 store/thread (wave writes 1 KB contiguous).
__global__ __launch_bounds__(256) void k_lin1_bn_relu(const float* __restrict__ W,
                                                      const float* __restrict__ b,
                                                      const float* __restrict__ g,
                                                      const float* __restrict__ bt,
                                                      const float* __restrict__ rm,
                                                      const float* __restrict__ rv) {
    __shared__ float Wsh[7][128];
    __shared__ float sSh[128], oSh[128];
    for (int v = threadIdx.x; v < 896; v += 256) Wsh[v >> 7][v & 127] = W[v];
    if (threadIdx.x < 128) {
        int c = threadIdx.x;
        float s = g[c] * rsqrtf(rv[c] + BN_EPS);
        sSh[c] = s;
        oSh[c] = fmaf(b[c] - rm[c], s, bt[c]);
    }
    __syncthreads();

    int t = blockIdx.x * 256 + threadIdx.x;   // node*16 + cgroup
    int i = t >> 4, c0 = (t & 15) * 8;        // grid exact: no bounds check
    float4 a03 = *(const float4*)(g_agg7 + (size_t)i * 8);
    float4 a47 = *(const float4*)(g_agg7 + (size_t)i * 8 + 4);
    float a[7] = {a03.x, a03.y, a03.z, a03.w, a47.x, a47.y, a47.z};
    float dv = g_dinv[i];
    float4 s04 = *(const float4*)(sSh + c0), s48 = *(const float4*)(sSh + c0 + 4);
    float4 o04 = *(const float4*)(oSh + c0), o48 = *(const float4*)(oSh + c0 + 4);
    float ss[8] = {s04.x, s04.y, s04.z, s04.w, s48.x, s48.y, s48.z, s48.w};
    float oo[8] = {o04.x, o04.y, o04.z, o04.w, o48.x, o48.y, o48.z, o48.w};
    float y[8];
#pragma unroll
    for (int j = 0; j < 8; ++j) {
        float z = 0.f;
#pragma unroll
        for (int k = 0; k < 7; ++k) z = fmaf(a[k], Wsh[k][c0 + j], z);
        z *= dv;
        y[j] = fmaxf(fmaf(z, ss[j], oo[j]), 0.f) * dv;   // premultiplied storage
    }
    *(uint4*)(g_hA + (size_t)i * 128 + c0) = pack8(y);
}

// ---------------- fused CSR-gather + MFMA GEMM + BN + ReLU ------------------
// 64 nodes/block, 256 threads (4 waves).
// ROUND-18: gather latency-bound. Interleave the thread's 4 node lists,
// 2 edges/list/round => up to 8 independent 16B row loads in flight/lane;
// sched_barrier(0) between issue loop and add loop keeps loads clustered.
// ROUND-19 POST-MORTEM: nontemporal hout stores were a 608 µs regression —
// nt bypasses L2 write-combining, so each 16B store became a partial-line
// HBM transaction (WRITE 359MB->1.77GB) plus merge fetches (FETCH
// 686MB->1.66GB). REVERTED to plain cached stores. Occupancy was 55% with
// launch_bounds (256,5); LDS (19,456B -> 8 blk/CU) and VGPR (48<=64) both
// allow 8 blocks/CU, so raise to (256,8) — more resident waves = more
// outstanding gather loads, which is what latency-boundness needs.
// GEMM: COLUMN-SPLIT waves — wave wv owns cols [wv*32, wv*32+32) x all 64
// rows. B-fragments loaded from global ONCE per block, issued before the
// post-gather barrier. LDS = As only (19,456 B). C layout (HW-verified):
// col=lane&15, row=quad*4+reg.

template <bool PRE, bool ATOB, int WSEL>
__global__ __launch_bounds__(256, 8) void k_agg_gemm(const float* __restrict__ b,
                                                     const float* __restrict__ g,
                                                     const float* __restrict__ bt,
                                                     const float* __restrict__ rm,
                                                     const float* __restrict__ rv) {
    const __half* __restrict__ hin  = ATOB ? g_hA : g_hB;
    __half* __restrict__       hout = ATOB ? g_hB : g_hA;
    const __half* __restrict__ WtG  = (WSEL == 0) ? g_wt2 : g_wt3;

    __shared__ __half As[64][152];          // 19,456 B
    const int tid = threadIdx.x;
    const int node0 = blockIdx.x * 64;

    // ---- gather phase: 4 node lists per thread, interleaved ----
    {
        const int slot = tid >> 4;          // 0..15
        const int c0 = (tid & 15) * 8;      // channel group (8 halfs = 16 B)
        float f[4][8];
        int e[4], e1[4];
#pragma unroll
        for (int p = 0; p < 4; ++p) {
            int i = node0 + p * 16 + slot;
            set8(*(const uint4*)(hin + (size_t)i * 128 + c0), f[p]);   // self term
            e[p]  = g_row_start[i];
            e1[p] = g_row_start[i + 1];
        }
        // rounds: issue up to 8 independent row loads (4 lists x 2), then add
        for (;;) {
            uint4 r[4][2];
            bool act[4];
            bool any = false;
#pragma unroll
            for (int p = 0; p < 4; ++p) {
                act[p] = (e[p] + 2 <= e1[p]);
                if (act[p]) {
                    int s0 = g_csr_src[e[p] + 0], s1 = g_csr_src[e[p] + 1];
                    r[p][0] = *(const uint4*)(hin + (size_t)s0 * 128 + c0);
                    r[p][1] = *(const uint4*)(hin + (size_t)s1 * 128 + c0);
                    e[p] += 2;
                    any = true;
                }
            }
            __builtin_amdgcn_sched_barrier(0);   // keep loads clustered ahead of adds
            if (!any) break;
#pragma unroll
            for (int p = 0; p < 4; ++p)
                if (act[p]) { add8(r[p][0], f[p]); add8(r[p][1], f[p]); }
        }
        // tail: at most 1 edge left per list
        {
            uint4 rt[4];
            bool act[4];
#pragma unroll
            for (int p = 0; p < 4; ++p) {
                act[p] = (e[p] < e1[p]);
                if (act[p]) {
                    int s = g_csr_src[e[p]];
                    rt[p] = *(const uint4*)(hin + (size_t)s * 128 + c0);
                }
            }
            __builtin_amdgcn_sched_barrier(0);
#pragma unroll
            for (int p = 0; p < 4; ++p)
                if (act[p]) add8(rt[p], f[p]);
        }
#pragma unroll
        for (int p = 0; p < 4; ++p)
            *(uint4*)(&As[p * 16 + slot][c0]) = pack8(f[p]);
    }

    const int wv = tid >> 6;        // wave 0..3 -> cols [wv*32, wv*32+32)
    const int lane = tid & 63;
    const int lm = lane & 15;       // m (a-frag) / n (b-frag) / col (c-frag)
    const int lq = lane >> 4;       // quad

    // B-fragments for this wave's 2 n-tiles, loaded once (latency hides
    // under the barrier).
    f16x8 bfr[2][4];
#pragma unroll
    for (int nt = 0; nt < 2; ++nt)
#pragma unroll
        for (int kb = 0; kb < 4; ++kb)
            __builtin_memcpy(&bfr[nt][kb],
                             WtG + (size_t)(wv * 32 + nt * 16 + lm) * 128 + kb * 32 + lq * 8, 16);

    __syncthreads();   // As visible to all waves

    // ---- MFMA: 4 m-tiles x 4 kb x 2 nt ----
    f32x4 acc[4][2];
#pragma unroll
    for (int mt = 0; mt < 4; ++mt)
#pragma unroll
        for (int nt = 0; nt < 2; ++nt) acc[mt][nt] = (f32x4){0.f, 0.f, 0.f, 0.f};

#pragma unroll
    for (int mt = 0; mt < 4; ++mt) {
#pragma unroll
        for (int kb = 0; kb < 4; ++kb) {
            f16x8 afr;
            __builtin_memcpy(&afr, &As[mt * 16 + lm][kb * 32 + lq * 8], 16);
#pragma unroll
            for (int nt = 0; nt < 2; ++nt)
                acc[mt][nt] = __builtin_amdgcn_mfma_f32_16x16x32_f16(afr, bfr[nt][kb], acc[mt][nt], 0, 0, 0);
        }
    }

    // per-m-tile dinv rows
    float4 dv4[4];
#pragma unroll
    for (int mt = 0; mt < 4; ++mt)
        dv4[mt] = *(const float4*)(g_dinv + node0 + mt * 16 + lq * 4);

    __syncthreads();   // all As reads done before overwrite

    // ---- epilogue: BN/ReLU, stage C in As, coalesced store ----
#pragma unroll
    for (int nt = 0; nt < 2; ++nt) {
        int c = wv * 32 + nt * 16 + lm;
        float s = g[c] * rsqrtf(rv[c] + BN_EPS);
        float o = fmaf(b[c] - rm[c], s, bt[c]);
#pragma unroll
        for (int mt = 0; mt < 4; ++mt) {
            float dvr[4] = {dv4[mt].x, dv4[mt].y, dv4[mt].z, dv4[mt].w};
#pragma unroll
            for (int r = 0; r < 4; ++r) {
                float pm = PRE ? dvr[r] : 1.0f;
                float y = fmaxf(fmaf(acc[mt][nt][r] * dvr[r], s, o), 0.f) * pm;
                As[mt * 16 + lq * 4 + r][c] = __float2half_rn(y);
            }
        }
    }
    __syncthreads();
#pragma unroll
    for (int i = 0; i < 4; ++i) {       // 1024 uint4 = 64 rows x 128 cols
        int u = tid + i * 256;          // 0..1023
        int row = u >> 4, cc = (u & 15) << 3;
        *(uint4*)(hout + (size_t)(node0 + row) * 128 + cc) = *(const uint4*)(&As[row][cc]);
    }
}

// ---------------- pooling + head ----------------

__global__ __launch_bounds__(256) void k_gstart(const int* __restrict__ batch) {
    int gidx = blockIdx.x * 256 + threadIdx.x;
    if (gidx > N_GRAPHS) return;
    int lo = 0, hi = N_NODES;
    while (lo < hi) {
        int mid = (lo + hi) >> 1;
        if (batch[mid] < gidx) lo = mid + 1; else hi = mid;
    }
    g_gstart[gidx] = lo;
}

__global__ __launch_bounds__(256) void k_pool_seg() {
    int t = blockIdx.x * 256 + threadIdx.x;
    int gi = t >> 4;
    if (gi >= N_GRAPHS) return;
    int c0 = (t & 15) * 8;
    int s0 = g_gstart[gi], s1 = g_gstart[gi + 1];
    float f[8] = {0.f, 0.f, 0.f, 0.f, 0.f, 0.f, 0.f, 0.f};
    for (int i = s0; i < s1; ++i)
        add8(*(const uint4*)(g_hA + (size_t)i * 128 + c0), f);
    float inv = 1.0f / (float)max(s1 - s0, 1);
    float* pooled = g_agg7;
    *(float4*)(pooled + (size_t)gi * 128 + c0)     = make_float4(f[0]*inv, f[1]*inv, f[2]*inv, f[3]*inv);
    *(float4*)(pooled + (size_t)gi * 128 + c0 + 4) = make_float4(f[4]*inv, f[5]*inv, f[6]*inv, f[7]*inv);
}

__global__ __launch_bounds__(256) void k_head1(const float* __restrict__ Wc1,
                                               const float* __restrict__ bc1) {
    int t = blockIdx.x * 256 + threadIdx.x;
    int gi = t >> 6, c = t & 63;
    if (gi >= N_GRAPHS) return;
    const float* pooled = g_agg7;
    float* hidden = g_agg7 + HIDDEN_OFF;
    float z = 0.f;
#pragma unroll 8
    for (int k = 0; k < 128; ++k) z = fmaf(pooled[gi * 128 + k], Wc1[k * 64 + c], z);
    hidden[t] = fmaxf(z + bc1[c], 0.f);
}

__global__ __launch_bounds__(256) void k_head2(const float* __restrict__ Wc2,
                                               const float* __restrict__ bc2,
                                               float* __restrict__ out) {
    int gi = blockIdx.x * 256 + threadIdx.x;
    if (gi >= N_GRAPHS) return;
    const float* hidden = g_agg7 + HIDDEN_OFF;
    float z = bc2[0];
#pragma unroll 8
    for (int k = 0; k < 64; ++k) z = fmaf(hidden[gi * 64 + k], Wc2[k], z);
    out[gi] = z;
}

// ---------------- launch ----------------

extern "C" void kernel_launch(void* const* d_in, const int* in_sizes, int n_in,
                              void* d_out, int out_size, void* d_ws, size_t ws_size,
                              hipStream_t stream) {
    const float* x     = (const float*)d_in[0];
    const int*   ei    = (const int*)d_in[1];
    const int*   batch = (const int*)d_in[2];
    const float* W1 = (const float*)d_in[3];
    const float* b1 = (const float*)d_in[4];
    const float* g1 = (const float*)d_in[5];
    const float* bt1= (const float*)d_in[6];
    const float* rm1= (const float*)d_in[7];
    const float* rv1= (const float*)d_in[8];
    const float* W2 = (const float*)d_in[9];
    const float* b2 = (const float*)d_in[10];
    const float* g2 = (const float*)d_in[11];
    const float* bt2= (const float*)d_in[12];
    const float* rm2= (const float*)d_in[13];
    const float* rv2= (const float*)d_in[14];
    const float* W3 = (const float*)d_in[15];
    const float* b3 = (const float*)d_in[16];
    const float* g3 = (const float*)d_in[17];
    const float* bt3= (const float*)d_in[18];
    const float* rm3= (const float*)d_in[19];
    const float* rv3= (const float*)d_in[20];
    const float* Wc1= (const float*)d_in[21];
    const float* bc1= (const float*)d_in[22];
    const float* Wc2= (const float*)d_in[23];
    const float* bc2= (const float*)d_in[24];
    float* outp = (float*)d_out;
    (void)d_ws; (void)ws_size; (void)n_in; (void)in_sizes;

    const int* srcp = ei;
    const int* dstp = ei + N_EDGES;

    // CSR build (by dst) + dinv (fused into scan1)
    k_zero_cnt<<<NBLK1, 256, 0, stream>>>();
    k_hist<<<(N_EDGES + 255) / 256, 256, 0, stream>>>(dstp);
    k_scan1<<<NBLK1, 256, 0, stream>>>();
    k_scan2<<<1, 256, 0, stream>>>();
    k_scan3<<<NBLK1, 256, 0, stream>>>();
    k_scatter<<<(N_EDGES + 255) / 256, 256, 0, stream>>>(srcp, dstp);

    // W2+W3 -> fp16 transposed (single launch)
    k_wt_both<<<128, 256, 0, stream>>>(W2, W3);

    // graph boundaries for pooling
    k_gstart<<<(N_GRAPHS + 1 + 255) / 256, 256, 0, stream>>>(batch);

    // layer 1: premultiply -> gather -> linear+BN+ReLU
    k_p7<<<(N_NODES + 255) / 256, 256, 0, stream>>>(x);
    k_agg7_csr<<<(N_NODES * 8) / 256, 256, 0, stream>>>();
    k_lin1_bn_relu<<<(N_NODES * 16) / 256, 256, 0, stream>>>(W1, b1, g1, bt1, rm1, rv1);

    // layers 2,3: fused gather + MFMA GEMM, ping-pong hA <-> hB
    k_agg_gemm<true,  true,  0><<<N_NODES / 64, 256, 0, stream>>>(b2, g2, bt2, rm2, rv2);
    k_agg_gemm<false, false, 1><<<N_NODES / 64, 256, 0, stream>>>(b3, g3, bt3, rm3, rv3);

    // segment-mean pool + head MLP
    k_pool_seg<<<(N_GRAPHS * 16) / 256, 256, 0, stream>>>();
    k_head1<<<(N_GRAPHS * 64) / 256, 256, 0, stream>>>(Wc1, bc1);
    k_head2<<<(N_GRAPHS + 255) / 256, 256, 0, stream>>>(Wc2, bc2, outp);
}

// Round 3
// 1552.119 us; speedup vs baseline: 2.9271x; 2.9271x over previous
//
#include <hip/hip_runtime.h>
#include <hip/hip_fp16.h>

#define N_NODES 1000000
#define N_EDGES 4000000
#define N_GRAPHS 32768
#define BN_EPS 1e-5f
#define NBLK1 3907   // ceil(N_NODES/256)

typedef _Float16 f16;
typedef f16   f16x8 __attribute__((ext_vector_type(8)));
typedef float f32x4 __attribute__((ext_vector_type(4)));

// ---------------------------------------------------------------------------
// Static device-global scratch (ws_size too small for the intermediates).
// fp16 ping-pong feature buffers keep the edge-gather set L3-resident.
// NOTE: device globals must ONLY be referenced from device code (round-6
// fault: host-side refs pass the host shadow address). Buffer selection is
// via template parameters.
// ---------------------------------------------------------------------------
__device__ __half g_hA[128000000];      // 256 MB node features
__device__ __half g_hB[128000000];      // 256 MB node features (aliased as f32 px in layer 1)
__device__ float  g_agg7[8400000];      //  33.6 MB layer-1 agg (8 floats/node, padded); later pooled+hidden
__device__ float  g_dinv[N_NODES];
__device__ int    g_rowcnt[N_NODES];
__device__ int    g_row_start[N_NODES + 1];
__device__ int    g_csr_src[N_EDGES];
__device__ int    g_part[NBLK1];
__device__ int    g_gstart[N_GRAPHS + 1];
__device__ __align__(16) __half g_wt2[16384];   // W2^T fp16 [n][k]
__device__ __align__(16) __half g_wt3[16384];   // W3^T fp16 [n][k]

#define HIDDEN_OFF 4259840   // pooled = g_agg7[0..4194304); hidden after pad

// ---------------- fp16 helpers (16 B = 8 halfs per lane) ----------------

__device__ __forceinline__ void set8(uint4 raw, float f[8]) {
    __half2 h; float2 a;
    __builtin_memcpy(&h, &raw.x, 4); a = __half22float2(h); f[0] = a.x; f[1] = a.y;
    __builtin_memcpy(&h, &raw.y, 4); a = __half22float2(h); f[2] = a.x; f[3] = a.y;
    __builtin_memcpy(&h, &raw.z, 4); a = __half22float2(h); f[4] = a.x; f[5] = a.y;
    __builtin_memcpy(&h, &raw.w, 4); a = __half22float2(h); f[6] = a.x; f[7] = a.y;
}
__device__ __forceinline__ void add8(uint4 raw, float f[8]) {
    __half2 h; float2 a;
    __builtin_memcpy(&h, &raw.x, 4); a = __half22float2(h); f[0] += a.x; f[1] += a.y;
    __builtin_memcpy(&h, &raw.y, 4); a = __half22float2(h); f[2] += a.x; f[3] += a.y;
    __builtin_memcpy(&h, &raw.z, 4); a = __half22float2(h); f[4] += a.x; f[5] += a.y;
    __builtin_memcpy(&h, &raw.w, 4); a = __half22float2(h); f[6] += a.x; f[7] += a.y;
}
__device__ __forceinline__ uint4 pack8(const float f[8]) {
    __half2 h0 = __floats2half2_rn(f[0], f[1]);
    __half2 h1 = __floats2half2_rn(f[2], f[3]);
    __half2 h2 = __floats2half2_rn(f[4], f[5]);
    __half2 h3 = __floats2half2_rn(f[6], f[7]);
    uint4 raw;
    __builtin_memcpy(&raw.x, &h0, 4);
    __builtin_memcpy(&raw.y, &h1, 4);
    __builtin_memcpy(&raw.z, &h2, 4);
    __builtin_memcpy(&raw.w, &h3, 4);
    return raw;
}

// ---------------- CSR build ----------------

__global__ __launch_bounds__(256) void k_zero_cnt() {
    int i = blockIdx.x * 256 + threadIdx.x;
    if (i < N_NODES) g_rowcnt[i] = 0;
}

__global__ __launch_bounds__(256) void k_hist(const int* __restrict__ dst) {
    int e = blockIdx.x * 256 + threadIdx.x;
    if (e < N_EDGES) atomicAdd(&g_rowcnt[dst[e]], 1);
}

// scan1 also computes dinv (reads rowcnt anyway) — saves a launch
__global__ __launch_bounds__(256) void k_scan1() {
    __shared__ int sh[256];
    int i = blockIdx.x * 256 + threadIdx.x;
    int v = (i < N_NODES) ? g_rowcnt[i] : 0;
    if (i < N_NODES) g_dinv[i] = rsqrtf((float)(1 + v));   // +1 self-loop
    sh[threadIdx.x] = v;
    __syncthreads();
#pragma unroll
    for (int off = 1; off < 256; off <<= 1) {
        int t = (threadIdx.x >= off) ? sh[threadIdx.x - off] : 0;
        __syncthreads();
        sh[threadIdx.x] += t;
        __syncthreads();
    }
    int incl = sh[threadIdx.x];
    if (i < N_NODES) g_row_start[i] = incl - v;
    if (threadIdx.x == 255) g_part[blockIdx.x] = incl;
}

__global__ __launch_bounds__(256) void k_scan2() {
    __shared__ int sh[256];
    int base = threadIdx.x * 16;
    int local[16];
    int s = 0;
#pragma unroll
    for (int k = 0; k < 16; ++k) {
        local[k] = (base + k < NBLK1) ? g_part[base + k] : 0;
        s += local[k];
    }
    sh[threadIdx.x] = s;
    __syncthreads();
#pragma unroll
    for (int off = 1; off < 256; off <<= 1) {
        int t = (threadIdx.x >= off) ? sh[threadIdx.x - off] : 0;
        __syncthreads();
        sh[threadIdx.x] += t;
        __syncthreads();
    }
    int carry = sh[threadIdx.x] - s;
#pragma unroll
    for (int k = 0; k < 16; ++k) {
        if (base + k < NBLK1) {
            int t = local[k];
            g_part[base + k] = carry;
            carry += t;
        }
    }
}

__global__ __launch_bounds__(256) void k_scan3() {
    int i = blockIdx.x * 256 + threadIdx.x;
    if (i < N_NODES) {
        g_row_start[i] += g_part[blockIdx.x];
        g_rowcnt[i] = 0;
    }
    if (i == 0) g_row_start[N_NODES] = N_EDGES;
}

__global__ __launch_bounds__(256) void k_scatter(const int* __restrict__ src,
                                                 const int* __restrict__ dst) {
    int e = blockIdx.x * 256 + threadIdx.x;
    if (e >= N_EDGES) return;
    int d = dst[e];
    int pos = g_row_start[d] + atomicAdd(&g_rowcnt[d], 1);
    g_csr_src[pos] = src[e];
}

// ---------------- W2+W3 transpose to fp16 (single launch) ----------------
// Wt[n][k] = (fp16) W[k][n]. Blocks 0..63 -> W2, 64..127 -> W3.

__global__ __launch_bounds__(256) void k_wt_both(const float* __restrict__ W2,
                                                 const float* __restrict__ W3) {
    int t = blockIdx.x * 256 + threadIdx.x;   // 0..32767
    int sel = t >> 14, u = t & 16383;
    int n = u & 127, k = u >> 7;
    __half* dst = sel ? g_wt3 : g_wt2;
    const float* W = sel ? W3 : W2;
    dst[n * 128 + k] = __float2half_rn(W[k * 128 + n]);
}

// ---------------- layer 1 ----------------

// px[i] = dinv[i]*x[i]  (px aliases g_hB as f32; dead once layer 2 runs)
__global__ __launch_bounds__(256) void k_p7(const float* __restrict__ x) {
    int i = blockIdx.x * 256 + threadIdx.x;
    if (i >= N_NODES) return;
    float w = g_dinv[i];
    float* px = (float*)g_hB;
#pragma unroll
    for (int k = 0; k < 7; ++k) px[i * 7 + k] = x[i * 7 + k] * w;
}

// agg7[d] = px[d] + sum px[s], 8 lanes/node, 4-deep MLP.
// Stored PADDED to 8 floats/node (c==7 writes 0) so lin1 loads aligned float4s.
__global__ __launch_bounds__(256) void k_agg7_csr() {
    int t = blockIdx.x * 256 + threadIdx.x;
    int i = t >> 3;
    int c = t & 7;
    if (i >= N_NODES) return;
    if (c == 7) { g_agg7[(size_t)i * 8 + 7] = 0.f; return; }
    const float* px = (const float*)g_hB;
    float acc = px[i * 7 + c];
    int e = g_row_start[i], e1 = g_row_start[i + 1];
    for (; e + 4 <= e1; e += 4) {
        int s0 = g_csr_src[e + 0], s1 = g_csr_src[e + 1];
        int s2 = g_csr_src[e + 2], s3 = g_csr_src[e + 3];
        float v0 = px[s0 * 7 + c], v1 = px[s1 * 7 + c];
        float v2 = px[s2 * 7 + c], v3 = px[s3 * 7 + c];
        acc += (v0 + v1) + (v2 + v3);
    }
    for (; e < e1; ++e) acc += px[g_csr_src[e] * 7 + c];
    g_agg7[(size_t)i * 8 + c] = acc;
}

// h1 = relu(bn(dinv*(agg7.W1) + b)); store q1 = dinv*h1 (fp16).
// 16 threads/node x 8 ch, aligned 2xfloat4 agg7 loads, W1+BN params staged
// in LDS, one uint4 fp16 store/thread (wave writes 1 KB contiguous).
__global__ __launch_bounds__(256) void k_lin1_bn_relu(const float* __restrict__ W,
                                                      const float* __restrict__ b,
                                                      const float* __restrict__ g,
                                                      const float* __restrict__ bt,
                                                      const float* __restrict__ rm,
                                                      const float* __restrict__ rv) {
    __shared__ float Wsh[7][128];
    __shared__ float sSh[128], oSh[128];
    for (int v = threadIdx.x; v < 896; v += 256) Wsh[v >> 7][v & 127] = W[v];
    if (threadIdx.x < 128) {
        int c = threadIdx.x;
        float s = g[c] * rsqrtf(rv[c] + BN_EPS);
        sSh[c] = s;
        oSh[c] = fmaf(b[c] - rm[c], s, bt[c]);
    }
    __syncthreads();

    int t = blockIdx.x * 256 + threadIdx.x;   // node*16 + cgroup
    int i = t >> 4, c0 = (t & 15) * 8;        // grid exact: no bounds check
    float4 a03 = *(const float4*)(g_agg7 + (size_t)i * 8);
    float4 a47 = *(const float4*)(g_agg7 + (size_t)i * 8 + 4);
    float a[7] = {a03.x, a03.y, a03.z, a03.w, a47.x, a47.y, a47.z};
    float dv = g_dinv[i];
    float4 s04 = *(const float4*)(sSh + c0), s48 = *(const float4*)(sSh + c0 + 4);
    float4 o04 = *(const float4*)(oSh + c0), o48 = *(const float4*)(oSh + c0 + 4);
    float ss[8] = {s04.x, s04.y, s04.z, s04.w, s48.x, s48.y, s48.z, s48.w};
    float oo[8] = {o04.x, o04.y, o04.z, o04.w, o48.x, o48.y, o48.z, o48.w};
    float y[8];
#pragma unroll
    for (int j = 0; j < 8; ++j) {
        float z = 0.f;
#pragma unroll
        for (int k = 0; k < 7; ++k) z = fmaf(a[k], Wsh[k][c0 + j], z);
        z *= dv;
        y[j] = fmaxf(fmaf(z, ss[j], oo[j]), 0.f) * dv;   // premultiplied storage
    }
    *(uint4*)(g_hA + (size_t)i * 128 + c0) = pack8(y);
}

// ---------------- fused CSR-gather + MFMA GEMM + BN + ReLU ------------------
// 64 nodes/block, 256 threads (4 waves).
// ROUND-20 POST-MORTEM LEDGER:
//  r18 (interleaved gather): f[4][8]+r[4][2] = 64+ live regs -> spills.
//  r19 (nt stores): partial-line HBM writes, WRITE 359MB->1.77GB. REVERTED.
//  r19b (launch_bounds (256,8)): total reg cap 64 -> arch squeezed to 32,
//       gather spilled to scratch every iter (FETCH 2.9GB WRITE 3.5GB,
//       92% occupancy yet 5x slower). REVERTED.
// Model: round-0 peak pressure = GEMM/epilogue phase (acc 32 + bfr 32 +
// dv4 16 + misc ~= 96 total) -> 5 waves/SIMD = 62.5% cap (measured 55%).
// THIS ROUND: (a) gather back to sequential 4-pass (known-good ~40 live),
// (b) kb-OUTER MFMA loop loads only 2 B-frags (8 regs) per kb from
// L2-resident g_wt* instead of holding all 8 frags (32 regs) across the
// phase, (c) launch_bounds (256,7): cap ~73 regs -> 7 blocks/CU.
// GEMM: COLUMN-SPLIT waves — wave wv owns cols [wv*32, wv*32+32) x all 64
// rows. LDS = As only (19,456 B). C layout (HW-verified): col=lane&15,
// row=quad*4+reg.

template <bool PRE, bool ATOB, int WSEL>
__global__ __launch_bounds__(256, 7) void k_agg_gemm(const float* __restrict__ b,
                                                     const float* __restrict__ g,
                                                     const float* __restrict__ bt,
                                                     const float* __restrict__ rm,
                                                     const float* __restrict__ rv) {
    const __half* __restrict__ hin  = ATOB ? g_hA : g_hB;
    __half* __restrict__       hout = ATOB ? g_hB : g_hA;
    const __half* __restrict__ WtG  = (WSEL == 0) ? g_wt2 : g_wt3;

    __shared__ __half As[64][152];          // 19,456 B
    const int tid = threadIdx.x;
    const int node0 = blockIdx.x * 64;

    // ---- gather phase (sequential 4-pass; low register pressure) ----
    {
        const int slot = tid >> 4;          // 0..15
        const int c0 = (tid & 15) * 8;      // channel group (8 halfs = 16 B)
#pragma unroll
        for (int pass = 0; pass < 4; ++pass) {
            int i = node0 + pass * 16 + slot;
            float f[8];
            set8(*(const uint4*)(hin + (size_t)i * 128 + c0), f);   // self term
            int e = g_row_start[i], e1 = g_row_start[i + 1];
            for (; e + 4 <= e1; e += 4) {
                int s0 = g_csr_src[e + 0], s1 = g_csr_src[e + 1];
                int s2 = g_csr_src[e + 2], s3 = g_csr_src[e + 3];
                uint4 r0 = *(const uint4*)(hin + (size_t)s0 * 128 + c0);
                uint4 r1 = *(const uint4*)(hin + (size_t)s1 * 128 + c0);
                uint4 r2 = *(const uint4*)(hin + (size_t)s2 * 128 + c0);
                uint4 r3 = *(const uint4*)(hin + (size_t)s3 * 128 + c0);
                add8(r0, f); add8(r1, f); add8(r2, f); add8(r3, f);
            }
            for (; e < e1; ++e) {
                int s = g_csr_src[e];
                add8(*(const uint4*)(hin + (size_t)s * 128 + c0), f);
            }
            int row = pass * 16 + slot;
            *(uint4*)(&As[row][c0]) = pack8(f);
        }
    }

    const int wv = tid >> 6;        // wave 0..3 -> cols [wv*32, wv*32+32)
    const int lane = tid & 63;
    const int lm = lane & 15;       // m (a-frag) / n (b-frag) / col (c-frag)
    const int lq = lane >> 4;       // quad

    __syncthreads();   // As visible to all waves

    // ---- MFMA: kb-outer so only 2 B-frags (8 regs) live at a time ----
    f32x4 acc[4][2];
#pragma unroll
    for (int mt = 0; mt < 4; ++mt)
#pragma unroll
        for (int nt = 0; nt < 2; ++nt) acc[mt][nt] = (f32x4){0.f, 0.f, 0.f, 0.f};

#pragma unroll
    for (int kb = 0; kb < 4; ++kb) {
        f16x8 bq[2];
#pragma unroll
        for (int nt = 0; nt < 2; ++nt)
            __builtin_memcpy(&bq[nt],
                             WtG + (size_t)(wv * 32 + nt * 16 + lm) * 128 + kb * 32 + lq * 8, 16);
#pragma unroll
        for (int mt = 0; mt < 4; ++mt) {
            f16x8 afr;
            __builtin_memcpy(&afr, &As[mt * 16 + lm][kb * 32 + lq * 8], 16);
#pragma unroll
            for (int nt = 0; nt < 2; ++nt)
                acc[mt][nt] = __builtin_amdgcn_mfma_f32_16x16x32_f16(afr, bq[nt], acc[mt][nt], 0, 0, 0);
        }
    }

    // per-m-tile dinv rows
    float4 dv4[4];
#pragma unroll
    for (int mt = 0; mt < 4; ++mt)
        dv4[mt] = *(const float4*)(g_dinv + node0 + mt * 16 + lq * 4);

    __syncthreads();   // all As reads done before overwrite

    // ---- epilogue: BN/ReLU, stage C in As, coalesced store ----
#pragma unroll
    for (int nt = 0; nt < 2; ++nt) {
        int c = wv * 32 + nt * 16 + lm;
        float s = g[c] * rsqrtf(rv[c] + BN_EPS);
        float o = fmaf(b[c] - rm[c], s, bt[c]);
#pragma unroll
        for (int mt = 0; mt < 4; ++mt) {
            float dvr[4] = {dv4[mt].x, dv4[mt].y, dv4[mt].z, dv4[mt].w};
#pragma unroll
            for (int r = 0; r < 4; ++r) {
                float pm = PRE ? dvr[r] : 1.0f;
                float y = fmaxf(fmaf(acc[mt][nt][r] * dvr[r], s, o), 0.f) * pm;
                As[mt * 16 + lq * 4 + r][c] = __float2half_rn(y);
            }
        }
    }
    __syncthreads();
#pragma unroll
    for (int i = 0; i < 4; ++i) {       // 1024 uint4 = 64 rows x 128 cols
        int u = tid + i * 256;          // 0..1023
        int row = u >> 4, cc = (u & 15) << 3;
        *(uint4*)(hout + (size_t)(node0 + row) * 128 + cc) = *(const uint4*)(&As[row][cc]);
    }
}

// ---------------- pooling + head ----------------

__global__ __launch_bounds__(256) void k_gstart(const int* __restrict__ batch) {
    int gidx = blockIdx.x * 256 + threadIdx.x;
    if (gidx > N_GRAPHS) return;
    int lo = 0, hi = N_NODES;
    while (lo < hi) {
        int mid = (lo + hi) >> 1;
        if (batch[mid] < gidx) lo = mid + 1; else hi = mid;
    }
    g_gstart[gidx] = lo;
}

__global__ __launch_bounds__(256) void k_pool_seg() {
    int t = blockIdx.x * 256 + threadIdx.x;
    int gi = t >> 4;
    if (gi >= N_GRAPHS) return;
    int c0 = (t & 15) * 8;
    int s0 = g_gstart[gi], s1 = g_gstart[gi + 1];
    float f[8] = {0.f, 0.f, 0.f, 0.f, 0.f, 0.f, 0.f, 0.f};
    for (int i = s0; i < s1; ++i)
        add8(*(const uint4*)(g_hA + (size_t)i * 128 + c0), f);
    float inv = 1.0f / (float)max(s1 - s0, 1);
    float* pooled = g_agg7;
    *(float4*)(pooled + (size_t)gi * 128 + c0)     = make_float4(f[0]*inv, f[1]*inv, f[2]*inv, f[3]*inv);
    *(float4*)(pooled + (size_t)gi * 128 + c0 + 4) = make_float4(f[4]*inv, f[5]*inv, f[6]*inv, f[7]*inv);
}

__global__ __launch_bounds__(256) void k_head1(const float* __restrict__ Wc1,
                                               const float* __restrict__ bc1) {
    int t = blockIdx.x * 256 + threadIdx.x;
    int gi = t >> 6, c = t & 63;
    if (gi >= N_GRAPHS) return;
    const float* pooled = g_agg7;
    float* hidden = g_agg7 + HIDDEN_OFF;
    float z = 0.f;
#pragma unroll 8
    for (int k = 0; k < 128; ++k) z = fmaf(pooled[gi * 128 + k], Wc1[k * 64 + c], z);
    hidden[t] = fmaxf(z + bc1[c], 0.f);
}

__global__ __launch_bounds__(256) void k_head2(const float* __restrict__ Wc2,
                                               const float* __restrict__ bc2,
                                               float* __restrict__ out) {
    int gi = blockIdx.x * 256 + threadIdx.x;
    if (gi >= N_GRAPHS) return;
    const float* hidden = g_agg7 + HIDDEN_OFF;
    float z = bc2[0];
#pragma unroll 8
    for (int k = 0; k < 64; ++k) z = fmaf(hidden[gi * 64 + k], Wc2[k], z);
    out[gi] = z;
}

// ---------------- launch ----------------

extern "C" void kernel_launch(void* const* d_in, const int* in_sizes, int n_in,
                              void* d_out, int out_size, void* d_ws, size_t ws_size,
                              hipStream_t stream) {
    const float* x     = (const float*)d_in[0];
    const int*   ei    = (const int*)d_in[1];
    const int*   batch = (const int*)d_in[2];
    const float* W1 = (const float*)d_in[3];
    const float* b1 = (const float*)d_in[4];
    const float* g1 = (const float*)d_in[5];
    const float* bt1= (const float*)d_in[6];
    const float* rm1= (const float*)d_in[7];
    const float* rv1= (const float*)d_in[8];
    const float* W2 = (const float*)d_in[9];
    const float* b2 = (const float*)d_in[10];
    const float* g2 = (const float*)d_in[11];
    const float* bt2= (const float*)d_in[12];
    const float* rm2= (const float*)d_in[13];
    const float* rv2= (const float*)d_in[14];
    const float* W3 = (const float*)d_in[15];
    const float* b3 = (const float*)d_in[16];
    const float* g3 = (const float*)d_in[17];
    const float* bt3= (const float*)d_in[18];
    const float* rm3= (const float*)d_in[19];
    const float* rv3= (const float*)d_in[20];
    const float* Wc1= (const float*)d_in[21];
    const float* bc1= (const float*)d_in[22];
    const float* Wc2= (const float*)d_in[23];
    const float* bc2= (const float*)d_in[24];
    float* outp = (float*)d_out;
    (void)d_ws; (void)ws_size; (void)n_in; (void)in_sizes;

    const int* srcp = ei;
    const int* dstp = ei + N_EDGES;

    // CSR build (by dst) + dinv (fused into scan1)
    k_zero_cnt<<<NBLK1, 256, 0, stream>>>();
    k_hist<<<(N_EDGES + 255) / 256, 256, 0, stream>>>(dstp);
    k_scan1<<<NBLK1, 256, 0, stream>>>();
    k_scan2<<<1, 256, 0, stream>>>();
    k_scan3<<<NBLK1, 256, 0, stream>>>();
    k_scatter<<<(N_EDGES + 255) / 256, 256, 0, stream>>>(srcp, dstp);

    // W2+W3 -> fp16 transposed (single launch)
    k_wt_both<<<128, 256, 0, stream>>>(W2, W3);

    // graph boundaries for pooling
    k_gstart<<<(N_GRAPHS + 1 + 255) / 256, 256, 0, stream>>>(batch);

    // layer 1: premultiply -> gather -> linear+BN+ReLU
    k_p7<<<(N_NODES + 255) / 256, 256, 0, stream>>>(x);
    k_agg7_csr<<<(N_NODES * 8) / 256, 256, 0, stream>>>();
    k_lin1_bn_relu<<<(N_NODES * 16) / 256, 256, 0, stream>>>(W1, b1, g1, bt1, rm1, rv1);

    // layers 2,3: fused gather + MFMA GEMM, ping-pong hA <-> hB
    k_agg_gemm<true,  true,  0><<<N_NODES / 64, 256, 0, stream>>>(b2, g2, bt2, rm2, rv2);
    k_agg_gemm<false, false, 1><<<N_NODES / 64, 256, 0, stream>>>(b3, g3, bt3, rm3, rv3);

    // segment-mean pool + head MLP
    k_pool_seg<<<(N_GRAPHS * 16) / 256, 256, 0, stream>>>();
    k_head1<<<(N_GRAPHS * 64) / 256, 256, 0, stream>>>(Wc1, bc1);
    k_head2<<<(N_GRAPHS + 255) / 256, 256, 0, stream>>>(Wc2, bc2, outp);
}

// Round 4
// 1328.307 us; speedup vs baseline: 3.4202x; 1.1685x over previous
//
#include <hip/hip_runtime.h>
#include <hip/hip_fp16.h>

#define N_NODES 1000000
#define N_EDGES 4000000
#define N_GRAPHS 32768
#define BN_EPS 1e-5f
#define NBLK1 3907   // ceil(N_NODES/256)

typedef _Float16 f16;
typedef f16   f16x8 __attribute__((ext_vector_type(8)));
typedef float f32x4 __attribute__((ext_vector_type(4)));
typedef float f32x2 __attribute__((ext_vector_type(2)));

// ---------------------------------------------------------------------------
// Static device-global scratch.
// ROUND-21: feature buffers on the GATHER-READ path switch to fp8 e4m3
// (OCP, native on gfx950): q1 (layer-2 input) and h2 (layer-3 input) are
// fp8 128 B/row; h3 (pool input, read once linearly) stays fp16.
// Rationale (r20 counters): gather is HBM-bound on random-row traffic —
// occupancy 55->79% moved dur -1%; hbm_bytes 1.21 GB @ 3.2 TB/s == dur.
// FETCH 900 MB vs 272 compulsory because fp16 read-set (256MB) + write
// stream (256MB) = 2x L3. fp8 halves rows AND makes the read set L3-fit.
// ---------------------------------------------------------------------------
__device__ __half g_hA[128000000];      // 256 MB: q1 fp8 (first 128 MB) -> h3 fp16
__device__ __half g_hB[128000000];      // 256 MB: px f32 (layer1) -> h2 fp8 (first 128 MB)
__device__ float  g_agg7[8400000];      //  33.6 MB layer-1 agg; later pooled+hidden
__device__ float  g_dinv[N_NODES];
__device__ int    g_rowcnt[N_NODES];
__device__ int    g_row_start[N_NODES + 1];
__device__ int    g_csr_src[N_EDGES];
__device__ int    g_part[NBLK1];
__device__ int    g_gstart[N_GRAPHS + 1];
__device__ __align__(16) __half g_wt2[16384];   // W2^T fp16 [n][k]
__device__ __align__(16) __half g_wt3[16384];   // W3^T fp16 [n][k]

#define HIDDEN_OFF 4259840   // pooled = g_agg7[0..4194304); hidden after pad

// ---------------- fp16 helpers (16 B = 8 halfs per lane) ----------------

__device__ __forceinline__ void set8(uint4 raw, float f[8]) {
    __half2 h; float2 a;
    __builtin_memcpy(&h, &raw.x, 4); a = __half22float2(h); f[0] = a.x; f[1] = a.y;
    __builtin_memcpy(&h, &raw.y, 4); a = __half22float2(h); f[2] = a.x; f[3] = a.y;
    __builtin_memcpy(&h, &raw.z, 4); a = __half22float2(h); f[4] = a.x; f[5] = a.y;
    __builtin_memcpy(&h, &raw.w, 4); a = __half22float2(h); f[6] = a.x; f[7] = a.y;
}
__device__ __forceinline__ uint4 pack8(const float f[8]) {
    __half2 h0 = __floats2half2_rn(f[0], f[1]);
    __half2 h1 = __floats2half2_rn(f[2], f[3]);
    __half2 h2 = __floats2half2_rn(f[4], f[5]);
    __half2 h3 = __floats2half2_rn(f[6], f[7]);
    uint4 raw;
    __builtin_memcpy(&raw.x, &h0, 4);
    __builtin_memcpy(&raw.y, &h1, 4);
    __builtin_memcpy(&raw.z, &h2, 4);
    __builtin_memcpy(&raw.w, &h3, 4);
    return raw;
}

// ---------------- fp8 e4m3 helpers (8 B = 8 fp8 per lane) ----------------
// Hardware v_cvt_pk_{f32_fp8,fp8_f32}; on gfx950 these are OCP e4m3.
// Byte order is self-consistent (same HW pairing both directions).

__device__ __forceinline__ void set8_fp8(uint2 raw, float f[8]) {
    f32x2 a;
    a = __builtin_amdgcn_cvt_pk_f32_fp8(raw.x, false); f[0] = a.x; f[1] = a.y;
    a = __builtin_amdgcn_cvt_pk_f32_fp8(raw.x, true);  f[2] = a.x; f[3] = a.y;
    a = __builtin_amdgcn_cvt_pk_f32_fp8(raw.y, false); f[4] = a.x; f[5] = a.y;
    a = __builtin_amdgcn_cvt_pk_f32_fp8(raw.y, true);  f[6] = a.x; f[7] = a.y;
}
__device__ __forceinline__ void add8_fp8(uint2 raw, float f[8]) {
    f32x2 a;
    a = __builtin_amdgcn_cvt_pk_f32_fp8(raw.x, false); f[0] += a.x; f[1] += a.y;
    a = __builtin_amdgcn_cvt_pk_f32_fp8(raw.x, true);  f[2] += a.x; f[3] += a.y;
    a = __builtin_amdgcn_cvt_pk_f32_fp8(raw.y, false); f[4] += a.x; f[5] += a.y;
    a = __builtin_amdgcn_cvt_pk_f32_fp8(raw.y, true);  f[6] += a.x; f[7] += a.y;
}
__device__ __forceinline__ uint2 pack8_fp8(const float f[8]) {
    int lo = 0, hi = 0;
    lo = __builtin_amdgcn_cvt_pk_fp8_f32(f[0], f[1], lo, false);
    lo = __builtin_amdgcn_cvt_pk_fp8_f32(f[2], f[3], lo, true);
    hi = __builtin_amdgcn_cvt_pk_fp8_f32(f[4], f[5], hi, false);
    hi = __builtin_amdgcn_cvt_pk_fp8_f32(f[6], f[7], hi, true);
    uint2 r; r.x = (unsigned)lo; r.y = (unsigned)hi; return r;
}

// ---------------- CSR build ----------------

__global__ __launch_bounds__(256) void k_zero_cnt() {
    int i = blockIdx.x * 256 + threadIdx.x;
    if (i < N_NODES) g_rowcnt[i] = 0;
}

__global__ __launch_bounds__(256) void k_hist(const int* __restrict__ dst) {
    int e = blockIdx.x * 256 + threadIdx.x;
    if (e < N_EDGES) atomicAdd(&g_rowcnt[dst[e]], 1);
}

// scan1 also computes dinv (reads rowcnt anyway) — saves a launch
__global__ __launch_bounds__(256) void k_scan1() {
    __shared__ int sh[256];
    int i = blockIdx.x * 256 + threadIdx.x;
    int v = (i < N_NODES) ? g_rowcnt[i] : 0;
    if (i < N_NODES) g_dinv[i] = rsqrtf((float)(1 + v));   // +1 self-loop
    sh[threadIdx.x] = v;
    __syncthreads();
#pragma unroll
    for (int off = 1; off < 256; off <<= 1) {
        int t = (threadIdx.x >= off) ? sh[threadIdx.x - off] : 0;
        __syncthreads();
        sh[threadIdx.x] += t;
        __syncthreads();
    }
    int incl = sh[threadIdx.x];
    if (i < N_NODES) g_row_start[i] = incl - v;
    if (threadIdx.x == 255) g_part[blockIdx.x] = incl;
}

__global__ __launch_bounds__(256) void k_scan2() {
    __shared__ int sh[256];
    int base = threadIdx.x * 16;
    int local[16];
    int s = 0;
#pragma unroll
    for (int k = 0; k < 16; ++k) {
        local[k] = (base + k < NBLK1) ? g_part[base + k] : 0;
        s += local[k];
    }
    sh[threadIdx.x] = s;
    __syncthreads();
#pragma unroll
    for (int off = 1; off < 256; off <<= 1) {
        int t = (threadIdx.x >= off) ? sh[threadIdx.x - off] : 0;
        __syncthreads();
        sh[threadIdx.x] += t;
        __syncthreads();
    }
    int carry = sh[threadIdx.x] - s;
#pragma unroll
    for (int k = 0; k < 16; ++k) {
        if (base + k < NBLK1) {
            int t = local[k];
            g_part[base + k] = carry;
            carry += t;
        }
    }
}

__global__ __launch_bounds__(256) void k_scan3() {
    int i = blockIdx.x * 256 + threadIdx.x;
    if (i < N_NODES) {
        g_row_start[i] += g_part[blockIdx.x];
        g_rowcnt[i] = 0;
    }
    if (i == 0) g_row_start[N_NODES] = N_EDGES;
}

__global__ __launch_bounds__(256) void k_scatter(const int* __restrict__ src,
                                                 const int* __restrict__ dst) {
    int e = blockIdx.x * 256 + threadIdx.x;
    if (e >= N_EDGES) return;
    int d = dst[e];
    int pos = g_row_start[d] + atomicAdd(&g_rowcnt[d], 1);
    g_csr_src[pos] = src[e];
}

// ---------------- W2+W3 transpose to fp16 (single launch) ----------------
// Wt[n][k] = (fp16) W[k][n]. Blocks 0..63 -> W2, 64..127 -> W3.

__global__ __launch_bounds__(256) void k_wt_both(const float* __restrict__ W2,
                                                 const float* __restrict__ W3) {
    int t = blockIdx.x * 256 + threadIdx.x;   // 0..32767
    int sel = t >> 14, u = t & 16383;
    int n = u & 127, k = u >> 7;
    __half* dst = sel ? g_wt3 : g_wt2;
    const float* W = sel ? W3 : W2;
    dst[n * 128 + k] = __float2half_rn(W[k * 128 + n]);
}

// ---------------- layer 1 ----------------

// px[i] = dinv[i]*x[i]  (px aliases g_hB as f32; dead once layer 2 runs)
__global__ __launch_bounds__(256) void k_p7(const float* __restrict__ x) {
    int i = blockIdx.x * 256 + threadIdx.x;
    if (i >= N_NODES) return;
    float w = g_dinv[i];
    float* px = (float*)g_hB;
#pragma unroll
    for (int k = 0; k < 7; ++k) px[i * 7 + k] = x[i * 7 + k] * w;
}

// agg7[d] = px[d] + sum px[s], 8 lanes/node, 4-deep MLP.
// Stored PADDED to 8 floats/node (c==7 writes 0) so lin1 loads aligned float4s.
__global__ __launch_bounds__(256) void k_agg7_csr() {
    int t = blockIdx.x * 256 + threadIdx.x;
    int i = t >> 3;
    int c = t & 7;
    if (i >= N_NODES) return;
    if (c == 7) { g_agg7[(size_t)i * 8 + 7] = 0.f; return; }
    const float* px = (const float*)g_hB;
    float acc = px[i * 7 + c];
    int e = g_row_start[i], e1 = g_row_start[i + 1];
    for (; e + 4 <= e1; e += 4) {
        int s0 = g_csr_src[e + 0], s1 = g_csr_src[e + 1];
        int s2 = g_csr_src[e + 2], s3 = g_csr_src[e + 3];
        float v0 = px[s0 * 7 + c], v1 = px[s1 * 7 + c];
        float v2 = px[s2 * 7 + c], v3 = px[s3 * 7 + c];
        acc += (v0 + v1) + (v2 + v3);
    }
    for (; e < e1; ++e) acc += px[g_csr_src[e] * 7 + c];
    g_agg7[(size_t)i * 8 + c] = acc;
}

// h1 = relu(bn(dinv*(agg7.W1) + b)); store q1 = dinv*h1 as FP8 (e4m3).
// 16 threads/node x 8 ch, W1+BN params staged in LDS, one uint2 fp8
// store/thread (wave writes 512 B contiguous).
__global__ __launch_bounds__(256) void k_lin1_bn_relu(const float* __restrict__ W,
                                                      const float* __restrict__ b,
                                                      const float* __restrict__ g,
                                                      const float* __restrict__ bt,
                                                      const float* __restrict__ rm,
                                                      const float* __restrict__ rv) {
    __shared__ float Wsh[7][128];
    __shared__ float sSh[128], oSh[128];
    for (int v = threadIdx.x; v < 896; v += 256) Wsh[v >> 7][v & 127] = W[v];
    if (threadIdx.x < 128) {
        int c = threadIdx.x;
        float s = g[c] * rsqrtf(rv[c] + BN_EPS);
        sSh[c] = s;
        oSh[c] = fmaf(b[c] - rm[c], s, bt[c]);
    }
    __syncthreads();

    int t = blockIdx.x * 256 + threadIdx.x;   // node*16 + cgroup
    int i = t >> 4, c0 = (t & 15) * 8;        // grid exact: no bounds check
    float4 a03 = *(const float4*)(g_agg7 + (size_t)i * 8);
    float4 a47 = *(const float4*)(g_agg7 + (size_t)i * 8 + 4);
    float a[7] = {a03.x, a03.y, a03.z, a03.w, a47.x, a47.y, a47.z};
    float dv = g_dinv[i];
    float4 s04 = *(const float4*)(sSh + c0), s48 = *(const float4*)(sSh + c0 + 4);
    float4 o04 = *(const float4*)(oSh + c0), o48 = *(const float4*)(oSh + c0 + 4);
    float ss[8] = {s04.x, s04.y, s04.z, s04.w, s48.x, s48.y, s48.z, s48.w};
    float oo[8] = {o04.x, o04.y, o04.z, o04.w, o48.x, o48.y, o48.z, o48.w};
    float y[8];
#pragma unroll
    for (int j = 0; j < 8; ++j) {
        float z = 0.f;
#pragma unroll
        for (int k = 0; k < 7; ++k) z = fmaf(a[k], Wsh[k][c0 + j], z);
        z *= dv;
        y[j] = fmaxf(fmaf(z, ss[j], oo[j]), 0.f) * dv;   // premultiplied storage
    }
    *(uint2*)((unsigned char*)g_hA + (size_t)i * 128 + (t & 15) * 8) = pack8_fp8(y);
}

// ---------------- fused CSR-gather + MFMA GEMM + BN + ReLU ------------------
// 64 nodes/block, 256 threads (4 waves).
// LEDGER:
//  r18 interleaved gather -> reg spills. REVERTED (sequential 4-pass).
//  r19 nt stores -> partial-line HBM writes, WRITE x5. REVERTED.
//  r19b launch_bounds(256,8) -> reg cap 64, scratch thrash. Now (256,7).
//  r20 occupancy 55->79% with dur unchanged => gather is HBM-traffic-bound
//      (1.21 GB @ 3.2 TB/s == 374 us), NOT latency-bound. Lever = bytes.
//  r21 THIS: hin rows fp8 e4m3 (128 B), f32 accumulate via v_cvt_pk_f32_fp8;
//      layer-2 output fp8 (OUT8), layer-3 output fp16 (pool accuracy).
//      Read set 128 MB -> L3-fit; expect FETCH 900 -> 200-450 MB.
// GEMM: COLUMN-SPLIT waves — wave wv owns cols [wv*32,+32) x all 64 rows.
// kb-outer B-frag loads (2 frags live) keep VGPR at 7-blocks/CU. LDS = As
// only (19,456 B). C layout (HW-verified): col=lane&15, row=quad*4+reg.

template <bool PRE, bool ATOB, int WSEL, bool OUT8>
__global__ __launch_bounds__(256, 7) void k_agg_gemm(const float* __restrict__ b,
                                                     const float* __restrict__ g,
                                                     const float* __restrict__ bt,
                                                     const float* __restrict__ rm,
                                                     const float* __restrict__ rv) {
    const unsigned char* __restrict__ hin8 =
        (const unsigned char*)(ATOB ? g_hA : g_hB);          // fp8 rows, 128 B
    __half* __restrict__ hout16 = ATOB ? g_hB : g_hA;        // fp16 rows, 256 B
    unsigned char* __restrict__ hout8 =
        (unsigned char*)(ATOB ? g_hB : g_hA);                // fp8 rows, 128 B
    const __half* __restrict__ WtG = (WSEL == 0) ? g_wt2 : g_wt3;

    __shared__ __half As[64][152];          // 19,456 B
    const int tid = threadIdx.x;
    const int node0 = blockIdx.x * 64;

    // ---- gather phase (sequential 4-pass; fp8 rows, f32 accumulate) ----
    {
        const int slot = tid >> 4;          // 0..15
        const int c0 = (tid & 15) * 8;      // 8 channels = 8 fp8 bytes = 8 As halfs
#pragma unroll
        for (int pass = 0; pass < 4; ++pass) {
            int i = node0 + pass * 16 + slot;
            float f[8];
            set8_fp8(*(const uint2*)(hin8 + (size_t)i * 128 + c0), f);   // self
            int e = g_row_start[i], e1 = g_row_start[i + 1];
            for (; e + 4 <= e1; e += 4) {
                int s0 = g_csr_src[e + 0], s1 = g_csr_src[e + 1];
                int s2 = g_csr_src[e + 2], s3 = g_csr_src[e + 3];
                uint2 r0 = *(const uint2*)(hin8 + (size_t)s0 * 128 + c0);
                uint2 r1 = *(const uint2*)(hin8 + (size_t)s1 * 128 + c0);
                uint2 r2 = *(const uint2*)(hin8 + (size_t)s2 * 128 + c0);
                uint2 r3 = *(const uint2*)(hin8 + (size_t)s3 * 128 + c0);
                add8_fp8(r0, f); add8_fp8(r1, f); add8_fp8(r2, f); add8_fp8(r3, f);
            }
            for (; e < e1; ++e) {
                int s = g_csr_src[e];
                add8_fp8(*(const uint2*)(hin8 + (size_t)s * 128 + c0), f);
            }
            int row = pass * 16 + slot;
            *(uint4*)(&As[row][c0]) = pack8(f);
        }
    }

    const int wv = tid >> 6;        // wave 0..3 -> cols [wv*32, wv*32+32)
    const int lane = tid & 63;
    const int lm = lane & 15;       // m (a-frag) / n (b-frag) / col (c-frag)
    const int lq = lane >> 4;       // quad

    __syncthreads();   // As visible to all waves

    // ---- MFMA: kb-outer so only 2 B-frags (8 regs) live at a time ----
    f32x4 acc[4][2];
#pragma unroll
    for (int mt = 0; mt < 4; ++mt)
#pragma unroll
        for (int nt = 0; nt < 2; ++nt) acc[mt][nt] = (f32x4){0.f, 0.f, 0.f, 0.f};

#pragma unroll
    for (int kb = 0; kb < 4; ++kb) {
        f16x8 bq[2];
#pragma unroll
        for (int nt = 0; nt < 2; ++nt)
            __builtin_memcpy(&bq[nt],
                             WtG + (size_t)(wv * 32 + nt * 16 + lm) * 128 + kb * 32 + lq * 8, 16);
#pragma unroll
        for (int mt = 0; mt < 4; ++mt) {
            f16x8 afr;
            __builtin_memcpy(&afr, &As[mt * 16 + lm][kb * 32 + lq * 8], 16);
#pragma unroll
            for (int nt = 0; nt < 2; ++nt)
                acc[mt][nt] = __builtin_amdgcn_mfma_f32_16x16x32_f16(afr, bq[nt], acc[mt][nt], 0, 0, 0);
        }
    }

    // per-m-tile dinv rows
    float4 dv4[4];
#pragma unroll
    for (int mt = 0; mt < 4; ++mt)
        dv4[mt] = *(const float4*)(g_dinv + node0 + mt * 16 + lq * 4);

    __syncthreads();   // all As reads done before overwrite

    // ---- epilogue: BN/ReLU, stage C (fp16) in As, coalesced store ----
#pragma unroll
    for (int nt = 0; nt < 2; ++nt) {
        int c = wv * 32 + nt * 16 + lm;
        float s = g[c] * rsqrtf(rv[c] + BN_EPS);
        float o = fmaf(b[c] - rm[c], s, bt[c]);
#pragma unroll
        for (int mt = 0; mt < 4; ++mt) {
            float dvr[4] = {dv4[mt].x, dv4[mt].y, dv4[mt].z, dv4[mt].w};
#pragma unroll
            for (int r = 0; r < 4; ++r) {
                float pm = PRE ? dvr[r] : 1.0f;
                float y = fmaxf(fmaf(acc[mt][nt][r] * dvr[r], s, o), 0.f) * pm;
                As[mt * 16 + lq * 4 + r][c] = __float2half_rn(y);
            }
        }
    }
    __syncthreads();
    if (OUT8) {
        // 64 rows x 128 fp8 bytes = 8 KB; 2 iters x 256 threads x 16 B.
#pragma unroll
        for (int i = 0; i < 2; ++i) {
            int u = tid + i * 256;              // 0..511
            int row = u >> 3, cb = (u & 7) * 16;   // 16 cols per thread
            float fa[8], fb[8];
            set8(*(const uint4*)(&As[row][cb]), fa);
            set8(*(const uint4*)(&As[row][cb + 8]), fb);
            uint2 pa = pack8_fp8(fa), pb = pack8_fp8(fb);
            uint4 v; v.x = pa.x; v.y = pa.y; v.z = pb.x; v.w = pb.y;
            *(uint4*)(hout8 + (size_t)(node0 + row) * 128 + cb) = v;
        }
    } else {
#pragma unroll
        for (int i = 0; i < 4; ++i) {       // 1024 uint4 = 64 rows x 128 cols
            int u = tid + i * 256;          // 0..1023
            int row = u >> 4, cc = (u & 15) << 3;
            *(uint4*)(hout16 + (size_t)(node0 + row) * 128 + cc) = *(const uint4*)(&As[row][cc]);
        }
    }
}

// ---------------- pooling + head ----------------

__global__ __launch_bounds__(256) void k_gstart(const int* __restrict__ batch) {
    int gidx = blockIdx.x * 256 + threadIdx.x;
    if (gidx > N_GRAPHS) return;
    int lo = 0, hi = N_NODES;
    while (lo < hi) {
        int mid = (lo + hi) >> 1;
        if (batch[mid] < gidx) lo = mid + 1; else hi = mid;
    }
    g_gstart[gidx] = lo;
}

__device__ __forceinline__ void add8h(uint4 raw, float f[8]) {
    __half2 h; float2 a;
    __builtin_memcpy(&h, &raw.x, 4); a = __half22float2(h); f[0] += a.x; f[1] += a.y;
    __builtin_memcpy(&h, &raw.y, 4); a = __half22float2(h); f[2] += a.x; f[3] += a.y;
    __builtin_memcpy(&h, &raw.z, 4); a = __half22float2(h); f[4] += a.x; f[5] += a.y;
    __builtin_memcpy(&h, &raw.w, 4); a = __half22float2(h); f[6] += a.x; f[7] += a.y;
}

__global__ __launch_bounds__(256) void k_pool_seg() {
    int t = blockIdx.x * 256 + threadIdx.x;
    int gi = t >> 4;
    if (gi >= N_GRAPHS) return;
    int c0 = (t & 15) * 8;
    int s0 = g_gstart[gi], s1 = g_gstart[gi + 1];
    float f[8] = {0.f, 0.f, 0.f, 0.f, 0.f, 0.f, 0.f, 0.f};
    for (int i = s0; i < s1; ++i)
        add8h(*(const uint4*)(g_hA + (size_t)i * 128 + c0), f);
    float inv = 1.0f / (float)max(s1 - s0, 1);
    float* pooled = g_agg7;
    *(float4*)(pooled + (size_t)gi * 128 + c0)     = make_float4(f[0]*inv, f[1]*inv, f[2]*inv, f[3]*inv);
    *(float4*)(pooled + (size_t)gi * 128 + c0 + 4) = make_float4(f[4]*inv, f[5]*inv, f[6]*inv, f[7]*inv);
}

__global__ __launch_bounds__(256) void k_head1(const float* __restrict__ Wc1,
                                               const float* __restrict__ bc1) {
    int t = blockIdx.x * 256 + threadIdx.x;
    int gi = t >> 6, c = t & 63;
    if (gi >= N_GRAPHS) return;
    const float* pooled = g_agg7;
    float* hidden = g_agg7 + HIDDEN_OFF;
    float z = 0.f;
#pragma unroll 8
    for (int k = 0; k < 128; ++k) z = fmaf(pooled[gi * 128 + k], Wc1[k * 64 + c], z);
    hidden[t] = fmaxf(z + bc1[c], 0.f);
}

__global__ __launch_bounds__(256) void k_head2(const float* __restrict__ Wc2,
                                               const float* __restrict__ bc2,
                                               float* __restrict__ out) {
    int gi = blockIdx.x * 256 + threadIdx.x;
    if (gi >= N_GRAPHS) return;
    const float* hidden = g_agg7 + HIDDEN_OFF;
    float z = bc2[0];
#pragma unroll 8
    for (int k = 0; k < 64; ++k) z = fmaf(hidden[gi * 64 + k], Wc2[k], z);
    out[gi] = z;
}

// ---------------- launch ----------------

extern "C" void kernel_launch(void* const* d_in, const int* in_sizes, int n_in,
                              void* d_out, int out_size, void* d_ws, size_t ws_size,
                              hipStream_t stream) {
    const float* x     = (const float*)d_in[0];
    const int*   ei    = (const int*)d_in[1];
    const int*   batch = (const int*)d_in[2];
    const float* W1 = (const float*)d_in[3];
    const float* b1 = (const float*)d_in[4];
    const float* g1 = (const float*)d_in[5];
    const float* bt1= (const float*)d_in[6];
    const float* rm1= (const float*)d_in[7];
    const float* rv1= (const float*)d_in[8];
    const float* W2 = (const float*)d_in[9];
    const float* b2 = (const float*)d_in[10];
    const float* g2 = (const float*)d_in[11];
    const float* bt2= (const float*)d_in[12];
    const float* rm2= (const float*)d_in[13];
    const float* rv2= (const float*)d_in[14];
    const float* W3 = (const float*)d_in[15];
    const float* b3 = (const float*)d_in[16];
    const float* g3 = (const float*)d_in[17];
    const float* bt3= (const float*)d_in[18];
    const float* rm3= (const float*)d_in[19];
    const float* rv3= (const float*)d_in[20];
    const float* Wc1= (const float*)d_in[21];
    const float* bc1= (const float*)d_in[22];
    const float* Wc2= (const float*)d_in[23];
    const float* bc2= (const float*)d_in[24];
    float* outp = (float*)d_out;
    (void)d_ws; (void)ws_size; (void)n_in; (void)in_sizes;

    const int* srcp = ei;
    const int* dstp = ei + N_EDGES;

    // CSR build (by dst) + dinv (fused into scan1)
    k_zero_cnt<<<NBLK1, 256, 0, stream>>>();
    k_hist<<<(N_EDGES + 255) / 256, 256, 0, stream>>>(dstp);
    k_scan1<<<NBLK1, 256, 0, stream>>>();
    k_scan2<<<1, 256, 0, stream>>>();
    k_scan3<<<NBLK1, 256, 0, stream>>>();
    k_scatter<<<(N_EDGES + 255) / 256, 256, 0, stream>>>(srcp, dstp);

    // W2+W3 -> fp16 transposed (single launch)
    k_wt_both<<<128, 256, 0, stream>>>(W2, W3);

    // graph boundaries for pooling
    k_gstart<<<(N_GRAPHS + 1 + 255) / 256, 256, 0, stream>>>(batch);

    // layer 1: premultiply -> gather -> linear+BN+ReLU (q1 stored fp8)
    k_p7<<<(N_NODES + 255) / 256, 256, 0, stream>>>(x);
    k_agg7_csr<<<(N_NODES * 8) / 256, 256, 0, stream>>>();
    k_lin1_bn_relu<<<(N_NODES * 16) / 256, 256, 0, stream>>>(W1, b1, g1, bt1, rm1, rv1);

    // layers 2,3: fused gather + MFMA GEMM
    // layer2: hin=g_hA fp8 (q1), hout=g_hB fp8 (h2)
    // layer3: hin=g_hB fp8 (h2), hout=g_hA fp16 (h3, pool input)
    k_agg_gemm<true,  true,  0, true ><<<N_NODES / 64, 256, 0, stream>>>(b2, g2, bt2, rm2, rv2);
    k_agg_gemm<false, false, 1, false><<<N_NODES / 64, 256, 0, stream>>>(b3, g3, bt3, rm3, rv3);

    // segment-mean pool + head MLP
    k_pool_seg<<<(N_GRAPHS * 16) / 256, 256, 0, stream>>>();
    k_head1<<<(N_GRAPHS * 64) / 256, 256, 0, stream>>>(Wc1, bc1);
    k_head2<<<(N_GRAPHS + 255) / 256, 256, 0, stream>>>(Wc2, bc2, outp);
}

// Round 5
// 1193.909 us; speedup vs baseline: 3.8053x; 1.1126x over previous
//
#include <hip/hip_runtime.h>
#include <hip/hip_fp16.h>

#define N_NODES 1000000
#define N_EDGES 4000000
#define N_GRAPHS 32768
#define BN_EPS 1e-5f
#define NBLK1 3907   // ceil(N_NODES/256)

typedef _Float16 f16;
typedef f16   f16x8 __attribute__((ext_vector_type(8)));
typedef float f32x4 __attribute__((ext_vector_type(4)));
typedef float f32x2 __attribute__((ext_vector_type(2)));

// ---------------------------------------------------------------------------
// Static device-global scratch.
// r21: gather-read features are fp8 e4m3 (q1, h2); r22: h3 is never
// materialized — layer-3 epilogue pools directly (batch is sorted).
// ---------------------------------------------------------------------------
__device__ __half g_hA[128000000];      // 256 MB: q1 fp8 (first 128 MB)
__device__ __half g_hB[128000000];      // 256 MB: px f32 (layer1) -> h2 fp8 (first 128 MB)
__device__ float  g_agg7[8400000];      //  33.6 MB layer-1 agg; later pooled-SUMS+hidden
__device__ float  g_dinv[N_NODES];
__device__ int    g_rowcnt[N_NODES];
__device__ int    g_row_start[N_NODES + 1];
__device__ int    g_csr_src[N_EDGES];
__device__ int    g_part[NBLK1];
__device__ int    g_gstart[N_GRAPHS + 1];
__device__ __align__(16) __half g_wt2[16384];   // W2^T fp16 [n][k]
__device__ __align__(16) __half g_wt3[16384];   // W3^T fp16 [n][k]

#define HIDDEN_OFF 4259840   // pooled sums = g_agg7[0..4194304); hidden after pad

// ---------------- fp16 helpers (16 B = 8 halfs per lane) ----------------

__device__ __forceinline__ void set8(uint4 raw, float f[8]) {
    __half2 h; float2 a;
    __builtin_memcpy(&h, &raw.x, 4); a = __half22float2(h); f[0] = a.x; f[1] = a.y;
    __builtin_memcpy(&h, &raw.y, 4); a = __half22float2(h); f[2] = a.x; f[3] = a.y;
    __builtin_memcpy(&h, &raw.z, 4); a = __half22float2(h); f[4] = a.x; f[5] = a.y;
    __builtin_memcpy(&h, &raw.w, 4); a = __half22float2(h); f[6] = a.x; f[7] = a.y;
}
__device__ __forceinline__ uint4 pack8(const float f[8]) {
    __half2 h0 = __floats2half2_rn(f[0], f[1]);
    __half2 h1 = __floats2half2_rn(f[2], f[3]);
    __half2 h2 = __floats2half2_rn(f[4], f[5]);
    __half2 h3 = __floats2half2_rn(f[6], f[7]);
    uint4 raw;
    __builtin_memcpy(&raw.x, &h0, 4);
    __builtin_memcpy(&raw.y, &h1, 4);
    __builtin_memcpy(&raw.z, &h2, 4);
    __builtin_memcpy(&raw.w, &h3, 4);
    return raw;
}

// ---------------- fp8 e4m3 helpers (8 B = 8 fp8 per lane) ----------------

__device__ __forceinline__ void set8_fp8(uint2 raw, float f[8]) {
    f32x2 a;
    a = __builtin_amdgcn_cvt_pk_f32_fp8(raw.x, false); f[0] = a.x; f[1] = a.y;
    a = __builtin_amdgcn_cvt_pk_f32_fp8(raw.x, true);  f[2] = a.x; f[3] = a.y;
    a = __builtin_amdgcn_cvt_pk_f32_fp8(raw.y, false); f[4] = a.x; f[5] = a.y;
    a = __builtin_amdgcn_cvt_pk_f32_fp8(raw.y, true);  f[6] = a.x; f[7] = a.y;
}
__device__ __forceinline__ void add8_fp8(uint2 raw, float f[8]) {
    f32x2 a;
    a = __builtin_amdgcn_cvt_pk_f32_fp8(raw.x, false); f[0] += a.x; f[1] += a.y;
    a = __builtin_amdgcn_cvt_pk_f32_fp8(raw.x, true);  f[2] += a.x; f[3] += a.y;
    a = __builtin_amdgcn_cvt_pk_f32_fp8(raw.y, false); f[4] += a.x; f[5] += a.y;
    a = __builtin_amdgcn_cvt_pk_f32_fp8(raw.y, true);  f[6] += a.x; f[7] += a.y;
}
__device__ __forceinline__ uint2 pack8_fp8(const float f[8]) {
    int lo = 0, hi = 0;
    lo = __builtin_amdgcn_cvt_pk_fp8_f32(f[0], f[1], lo, false);
    lo = __builtin_amdgcn_cvt_pk_fp8_f32(f[2], f[3], lo, true);
    hi = __builtin_amdgcn_cvt_pk_fp8_f32(f[4], f[5], hi, false);
    hi = __builtin_amdgcn_cvt_pk_fp8_f32(f[6], f[7], hi, true);
    uint2 r; r.x = (unsigned)lo; r.y = (unsigned)hi; return r;
}

// ---------------- CSR build ----------------

__global__ __launch_bounds__(256) void k_zero_cnt() {
    int i = blockIdx.x * 256 + threadIdx.x;
    if (i < N_NODES) g_rowcnt[i] = 0;
}

__global__ __launch_bounds__(256) void k_hist(const int* __restrict__ dst) {
    int e = blockIdx.x * 256 + threadIdx.x;
    if (e < N_EDGES) atomicAdd(&g_rowcnt[dst[e]], 1);
}

// scan1 also computes dinv (reads rowcnt anyway) — saves a launch
__global__ __launch_bounds__(256) void k_scan1() {
    __shared__ int sh[256];
    int i = blockIdx.x * 256 + threadIdx.x;
    int v = (i < N_NODES) ? g_rowcnt[i] : 0;
    if (i < N_NODES) g_dinv[i] = rsqrtf((float)(1 + v));   // +1 self-loop
    sh[threadIdx.x] = v;
    __syncthreads();
#pragma unroll
    for (int off = 1; off < 256; off <<= 1) {
        int t = (threadIdx.x >= off) ? sh[threadIdx.x - off] : 0;
        __syncthreads();
        sh[threadIdx.x] += t;
        __syncthreads();
    }
    int incl = sh[threadIdx.x];
    if (i < N_NODES) g_row_start[i] = incl - v;
    if (threadIdx.x == 255) g_part[blockIdx.x] = incl;
}

__global__ __launch_bounds__(256) void k_scan2() {
    __shared__ int sh[256];
    int base = threadIdx.x * 16;
    int local[16];
    int s = 0;
#pragma unroll
    for (int k = 0; k < 16; ++k) {
        local[k] = (base + k < NBLK1) ? g_part[base + k] : 0;
        s += local[k];
    }
    sh[threadIdx.x] = s;
    __syncthreads();
#pragma unroll
    for (int off = 1; off < 256; off <<= 1) {
        int t = (threadIdx.x >= off) ? sh[threadIdx.x - off] : 0;
        __syncthreads();
        sh[threadIdx.x] += t;
        __syncthreads();
    }
    int carry = sh[threadIdx.x] - s;
#pragma unroll
    for (int k = 0; k < 16; ++k) {
        if (base + k < NBLK1) {
            int t = local[k];
            g_part[base + k] = carry;
            carry += t;
        }
    }
}

__global__ __launch_bounds__(256) void k_scan3() {
    int i = blockIdx.x * 256 + threadIdx.x;
    if (i < N_NODES) {
        g_row_start[i] += g_part[blockIdx.x];
        g_rowcnt[i] = 0;
    }
    if (i == 0) g_row_start[N_NODES] = N_EDGES;
}

__global__ __launch_bounds__(256) void k_scatter(const int* __restrict__ src,
                                                 const int* __restrict__ dst) {
    int e = blockIdx.x * 256 + threadIdx.x;
    if (e >= N_EDGES) return;
    int d = dst[e];
    int pos = g_row_start[d] + atomicAdd(&g_rowcnt[d], 1);
    g_csr_src[pos] = src[e];
}

// ---------------- W2+W3 transpose to fp16 (single launch) ----------------

__global__ __launch_bounds__(256) void k_wt_both(const float* __restrict__ W2,
                                                 const float* __restrict__ W3) {
    int t = blockIdx.x * 256 + threadIdx.x;   // 0..32767
    int sel = t >> 14, u = t & 16383;
    int n = u & 127, k = u >> 7;
    __half* dst = sel ? g_wt3 : g_wt2;
    const float* W = sel ? W3 : W2;
    dst[n * 128 + k] = __float2half_rn(W[k * 128 + n]);
}

// ---------------- layer 1 ----------------

// px[i] = dinv[i]*x[i]  (px aliases g_hB as f32; dead once layer 2 runs)
__global__ __launch_bounds__(256) void k_p7(const float* __restrict__ x) {
    int i = blockIdx.x * 256 + threadIdx.x;
    if (i >= N_NODES) return;
    float w = g_dinv[i];
    float* px = (float*)g_hB;
#pragma unroll
    for (int k = 0; k < 7; ++k) px[i * 7 + k] = x[i * 7 + k] * w;
}

// agg7[d] = px[d] + sum px[s], 8 lanes/node, 4-deep MLP.
__global__ __launch_bounds__(256) void k_agg7_csr() {
    int t = blockIdx.x * 256 + threadIdx.x;
    int i = t >> 3;
    int c = t & 7;
    if (i >= N_NODES) return;
    if (c == 7) { g_agg7[(size_t)i * 8 + 7] = 0.f; return; }
    const float* px = (const float*)g_hB;
    float acc = px[i * 7 + c];
    int e = g_row_start[i], e1 = g_row_start[i + 1];
    for (; e + 4 <= e1; e += 4) {
        int s0 = g_csr_src[e + 0], s1 = g_csr_src[e + 1];
        int s2 = g_csr_src[e + 2], s3 = g_csr_src[e + 3];
        float v0 = px[s0 * 7 + c], v1 = px[s1 * 7 + c];
        float v2 = px[s2 * 7 + c], v3 = px[s3 * 7 + c];
        acc += (v0 + v1) + (v2 + v3);
    }
    for (; e < e1; ++e) acc += px[g_csr_src[e] * 7 + c];
    g_agg7[(size_t)i * 8 + c] = acc;
}

// h1 = relu(bn(dinv*(agg7.W1) + b)); store q1 = dinv*h1 as FP8 (e4m3).
__global__ __launch_bounds__(256) void k_lin1_bn_relu(const float* __restrict__ W,
                                                      const float* __restrict__ b,
                                                      const float* __restrict__ g,
                                                      const float* __restrict__ bt,
                                                      const float* __restrict__ rm,
                                                      const float* __restrict__ rv) {
    __shared__ float Wsh[7][128];
    __shared__ float sSh[128], oSh[128];
    for (int v = threadIdx.x; v < 896; v += 256) Wsh[v >> 7][v & 127] = W[v];
    if (threadIdx.x < 128) {
        int c = threadIdx.x;
        float s = g[c] * rsqrtf(rv[c] + BN_EPS);
        sSh[c] = s;
        oSh[c] = fmaf(b[c] - rm[c], s, bt[c]);
    }
    __syncthreads();

    int t = blockIdx.x * 256 + threadIdx.x;   // node*16 + cgroup
    int i = t >> 4, c0 = (t & 15) * 8;        // grid exact: no bounds check
    float4 a03 = *(const float4*)(g_agg7 + (size_t)i * 8);
    float4 a47 = *(const float4*)(g_agg7 + (size_t)i * 8 + 4);
    float a[7] = {a03.x, a03.y, a03.z, a03.w, a47.x, a47.y, a47.z};
    float dv = g_dinv[i];
    float4 s04 = *(const float4*)(sSh + c0), s48 = *(const float4*)(sSh + c0 + 4);
    float4 o04 = *(const float4*)(oSh + c0), o48 = *(const float4*)(oSh + c0 + 4);
    float ss[8] = {s04.x, s04.y, s04.z, s04.w, s48.x, s48.y, s48.z, s48.w};
    float oo[8] = {o04.x, o04.y, o04.z, o04.w, o48.x, o48.y, o48.z, o48.w};
    float y[8];
#pragma unroll
    for (int j = 0; j < 8; ++j) {
        float z = 0.f;
#pragma unroll
        for (int k = 0; k < 7; ++k) z = fmaf(a[k], Wsh[k][c0 + j], z);
        z *= dv;
        y[j] = fmaxf(fmaf(z, ss[j], oo[j]), 0.f) * dv;   // premultiplied storage
    }
    *(uint2*)((unsigned char*)g_hA + (size_t)i * 128 + (t & 15) * 8) = pack8_fp8(y);
}

// zero the pooled-sum accumulator (16.78 MB) before layer-3's atomics
__global__ __launch_bounds__(256) void k_zero_pool() {
    int t = blockIdx.x * 256 + threadIdx.x;          // 0..1048575
    *(float4*)(g_agg7 + (size_t)t * 4) = make_float4(0.f, 0.f, 0.f, 0.f);
}

// ---------------- fused CSR-gather + MFMA GEMM + BN + ReLU ------------------
// 64 nodes/block, 256 threads (4 waves).
// LEDGER:
//  r18 interleaved gather -> reg spills. REVERTED (sequential 4-pass).
//  r19 nt stores -> partial-line HBM writes, WRITE x5. REVERTED.
//  r19b launch_bounds(256,8) -> reg cap 64, scratch thrash. Now (256,7).
//  r20 occupancy 55->79% with dur unchanged => HBM-traffic-bound. Lever=bytes.
//  r21 fp8 e4m3 rows for gather reads: 374 -> 277 us, absmax unchanged.
//      Remaining layer-3 re-reads (FETCH 567 vs ~150 compulsory): its own
//      256 MB fp16 h3 write stream evicts the read set from L3.
//  r22 THIS: h3 never materialized. Layer-3 epilogue pools in-block (batch
//      is SORTED; 64-node block spans ~3 graphs): run-length sum the 64
//      staged C rows per channel, atomicAdd f32 partial sums into pooled
//      (16 MB, L2/L3-resident). Kills the 256 MB write + 256 MB pool read.
// GEMM: COLUMN-SPLIT waves — wave wv owns cols [wv*32,+32) x all 64 rows.
// kb-outer B-frag loads. LDS = As (19,456 B) + bsh (256 B). C layout
// (HW-verified): col=lane&15, row=quad*4+reg.
// OUTMODE: 1 = fp8 row store (layer 2), 2 = fused pool (layer 3).

template <bool PRE, bool ATOB, int WSEL, int OUTMODE>
__global__ __launch_bounds__(256, 7) void k_agg_gemm(const float* __restrict__ b,
                                                     const float* __restrict__ g,
                                                     const float* __restrict__ bt,
                                                     const float* __restrict__ rm,
                                                     const float* __restrict__ rv,
                                                     const int* __restrict__ batch) {
    const unsigned char* __restrict__ hin8 =
        (const unsigned char*)(ATOB ? g_hA : g_hB);          // fp8 rows, 128 B
    unsigned char* __restrict__ hout8 =
        (unsigned char*)(ATOB ? g_hB : g_hA);                // fp8 rows, 128 B
    const __half* __restrict__ WtG = (WSEL == 0) ? g_wt2 : g_wt3;

    __shared__ __half As[64][152];          // 19,456 B
    __shared__ int bsh[64];
    const int tid = threadIdx.x;
    const int node0 = blockIdx.x * 64;

    // ---- gather phase (sequential 4-pass; fp8 rows, f32 accumulate) ----
    {
        const int slot = tid >> 4;          // 0..15
        const int c0 = (tid & 15) * 8;      // 8 channels = 8 fp8 bytes
#pragma unroll
        for (int pass = 0; pass < 4; ++pass) {
            int i = node0 + pass * 16 + slot;
            float f[8];
            set8_fp8(*(const uint2*)(hin8 + (size_t)i * 128 + c0), f);   // self
            int e = g_row_start[i], e1 = g_row_start[i + 1];
            for (; e + 4 <= e1; e += 4) {
                int s0 = g_csr_src[e + 0], s1 = g_csr_src[e + 1];
                int s2 = g_csr_src[e + 2], s3 = g_csr_src[e + 3];
                uint2 r0 = *(const uint2*)(hin8 + (size_t)s0 * 128 + c0);
                uint2 r1 = *(const uint2*)(hin8 + (size_t)s1 * 128 + c0);
                uint2 r2 = *(const uint2*)(hin8 + (size_t)s2 * 128 + c0);
                uint2 r3 = *(const uint2*)(hin8 + (size_t)s3 * 128 + c0);
                add8_fp8(r0, f); add8_fp8(r1, f); add8_fp8(r2, f); add8_fp8(r3, f);
            }
            for (; e < e1; ++e) {
                int s = g_csr_src[e];
                add8_fp8(*(const uint2*)(hin8 + (size_t)s * 128 + c0), f);
            }
            int row = pass * 16 + slot;
            *(uint4*)(&As[row][c0]) = pack8(f);
        }
    }

    const int wv = tid >> 6;        // wave 0..3 -> cols [wv*32, wv*32+32)
    const int lane = tid & 63;
    const int lm = lane & 15;       // m (a-frag) / n (b-frag) / col (c-frag)
    const int lq = lane >> 4;       // quad

    __syncthreads();   // As visible to all waves

    // ---- MFMA: kb-outer so only 2 B-frags (8 regs) live at a time ----
    f32x4 acc[4][2];
#pragma unroll
    for (int mt = 0; mt < 4; ++mt)
#pragma unroll
        for (int nt = 0; nt < 2; ++nt) acc[mt][nt] = (f32x4){0.f, 0.f, 0.f, 0.f};

#pragma unroll
    for (int kb = 0; kb < 4; ++kb) {
        f16x8 bq[2];
#pragma unroll
        for (int nt = 0; nt < 2; ++nt)
            __builtin_memcpy(&bq[nt],
                             WtG + (size_t)(wv * 32 + nt * 16 + lm) * 128 + kb * 32 + lq * 8, 16);
#pragma unroll
        for (int mt = 0; mt < 4; ++mt) {
            f16x8 afr;
            __builtin_memcpy(&afr, &As[mt * 16 + lm][kb * 32 + lq * 8], 16);
#pragma unroll
            for (int nt = 0; nt < 2; ++nt)
                acc[mt][nt] = __builtin_amdgcn_mfma_f32_16x16x32_f16(afr, bq[nt], acc[mt][nt], 0, 0, 0);
        }
    }

    // per-m-tile dinv rows
    float4 dv4[4];
#pragma unroll
    for (int mt = 0; mt < 4; ++mt)
        dv4[mt] = *(const float4*)(g_dinv + node0 + mt * 16 + lq * 4);

    if (OUTMODE == 2 && tid < 64) bsh[tid] = batch[node0 + tid];

    __syncthreads();   // all As reads done before overwrite

    // ---- epilogue: BN/ReLU, stage C (fp16) in As ----
#pragma unroll
    for (int nt = 0; nt < 2; ++nt) {
        int c = wv * 32 + nt * 16 + lm;
        float s = g[c] * rsqrtf(rv[c] + BN_EPS);
        float o = fmaf(b[c] - rm[c], s, bt[c]);
#pragma unroll
        for (int mt = 0; mt < 4; ++mt) {
            float dvr[4] = {dv4[mt].x, dv4[mt].y, dv4[mt].z, dv4[mt].w};
#pragma unroll
            for (int r = 0; r < 4; ++r) {
                float pm = PRE ? dvr[r] : 1.0f;
                float y = fmaxf(fmaf(acc[mt][nt][r] * dvr[r], s, o), 0.f) * pm;
                As[mt * 16 + lq * 4 + r][c] = __float2half_rn(y);
            }
        }
    }
    __syncthreads();

    if (OUTMODE == 1) {
        // 64 rows x 128 fp8 bytes = 8 KB; 2 iters x 256 threads x 16 B.
#pragma unroll
        for (int i = 0; i < 2; ++i) {
            int u = tid + i * 256;                 // 0..511
            int row = u >> 3, cb = (u & 7) * 16;   // 16 cols per thread
            float fa[8], fb[8];
            set8(*(const uint4*)(&As[row][cb]), fa);
            set8(*(const uint4*)(&As[row][cb + 8]), fb);
            uint2 pa = pack8_fp8(fa), pb = pack8_fp8(fb);
            uint4 v; v.x = pa.x; v.y = pa.y; v.z = pb.x; v.w = pb.y;
            *(uint4*)(hout8 + (size_t)(node0 + row) * 128 + cb) = v;
        }
    } else {
        // fused segment-sum pooling: batch sorted -> run-length sum the 64
        // rows by graph id. thread t: channel tid&127, rows [r0, r0+32).
        // Branches are wave-uniform (all lanes share the row sequence).
        const int c = tid & 127;
        const int r0 = (tid >> 7) * 32;
        float accp = 0.f;
        int g0 = bsh[r0];
        for (int row = r0; row < r0 + 32; ++row) {
            int gg = bsh[row];
            if (gg != g0) {
                atomicAdd(&g_agg7[(size_t)g0 * 128 + c], accp);
                accp = 0.f; g0 = gg;
            }
            accp += __half2float(As[row][c]);
        }
        atomicAdd(&g_agg7[(size_t)g0 * 128 + c], accp);
    }
}

// ---------------- pooling boundaries + head ----------------

__global__ __launch_bounds__(256) void k_gstart(const int* __restrict__ batch) {
    int gidx = blockIdx.x * 256 + threadIdx.x;
    if (gidx > N_GRAPHS) return;
    int lo = 0, hi = N_NODES;
    while (lo < hi) {
        int mid = (lo + hi) >> 1;
        if (batch[mid] < gidx) lo = mid + 1; else hi = mid;
    }
    g_gstart[gidx] = lo;
}

// hidden = relu((pooled_sum/cnt) @ Wc1 + bc1); pooled holds SUMS (r22)
__global__ __launch_bounds__(256) void k_head1(const float* __restrict__ Wc1,
                                               const float* __restrict__ bc1) {
    int t = blockIdx.x * 256 + threadIdx.x;
    int gi = t >> 6, c = t & 63;
    if (gi >= N_GRAPHS) return;
    const float* pooled = g_agg7;
    float* hidden = g_agg7 + HIDDEN_OFF;
    int cnt = g_gstart[gi + 1] - g_gstart[gi];
    float inv = 1.0f / (float)max(cnt, 1);
    float z = 0.f;
#pragma unroll 8
    for (int k = 0; k < 128; ++k) z = fmaf(pooled[gi * 128 + k], Wc1[k * 64 + c], z);
    hidden[t] = fmaxf(fmaf(z, inv, bc1[c]), 0.f);
}

__global__ __launch_bounds__(256) void k_head2(const float* __restrict__ Wc2,
                                               const float* __restrict__ bc2,
                                               float* __restrict__ out) {
    int gi = blockIdx.x * 256 + threadIdx.x;
    if (gi >= N_GRAPHS) return;
    const float* hidden = g_agg7 + HIDDEN_OFF;
    float z = bc2[0];
#pragma unroll 8
    for (int k = 0; k < 64; ++k) z = fmaf(hidden[gi * 64 + k], Wc2[k], z);
    out[gi] = z;
}

// ---------------- launch ----------------

extern "C" void kernel_launch(void* const* d_in, const int* in_sizes, int n_in,
                              void* d_out, int out_size, void* d_ws, size_t ws_size,
                              hipStream_t stream) {
    const float* x     = (const float*)d_in[0];
    const int*   ei    = (const int*)d_in[1];
    const int*   batch = (const int*)d_in[2];
    const float* W1 = (const float*)d_in[3];
    const float* b1 = (const float*)d_in[4];
    const float* g1 = (const float*)d_in[5];
    const float* bt1= (const float*)d_in[6];
    const float* rm1= (const float*)d_in[7];
    const float* rv1= (const float*)d_in[8];
    const float* W2 = (const float*)d_in[9];
    const float* b2 = (const float*)d_in[10];
    const float* g2 = (const float*)d_in[11];
    const float* bt2= (const float*)d_in[12];
    const float* rm2= (const float*)d_in[13];
    const float* rv2= (const float*)d_in[14];
    const float* W3 = (const float*)d_in[15];
    const float* b3 = (const float*)d_in[16];
    const float* g3 = (const float*)d_in[17];
    const float* bt3= (const float*)d_in[18];
    const float* rm3= (const float*)d_in[19];
    const float* rv3= (const float*)d_in[20];
    const float* Wc1= (const float*)d_in[21];
    const float* bc1= (const float*)d_in[22];
    const float* Wc2= (const float*)d_in[23];
    const float* bc2= (const float*)d_in[24];
    float* outp = (float*)d_out;
    (void)d_ws; (void)ws_size; (void)n_in; (void)in_sizes;

    const int* srcp = ei;
    const int* dstp = ei + N_EDGES;

    // CSR build (by dst) + dinv (fused into scan1)
    k_zero_cnt<<<NBLK1, 256, 0, stream>>>();
    k_hist<<<(N_EDGES + 255) / 256, 256, 0, stream>>>(dstp);
    k_scan1<<<NBLK1, 256, 0, stream>>>();
    k_scan2<<<1, 256, 0, stream>>>();
    k_scan3<<<NBLK1, 256, 0, stream>>>();
    k_scatter<<<(N_EDGES + 255) / 256, 256, 0, stream>>>(srcp, dstp);

    // W2+W3 -> fp16 transposed (single launch)
    k_wt_both<<<128, 256, 0, stream>>>(W2, W3);

    // graph boundaries for pooling
    k_gstart<<<(N_GRAPHS + 1 + 255) / 256, 256, 0, stream>>>(batch);

    // layer 1: premultiply -> gather -> linear+BN+ReLU (q1 stored fp8)
    k_p7<<<(N_NODES + 255) / 256, 256, 0, stream>>>(x);
    k_agg7_csr<<<(N_NODES * 8) / 256, 256, 0, stream>>>();
    k_lin1_bn_relu<<<(N_NODES * 16) / 256, 256, 0, stream>>>(W1, b1, g1, bt1, rm1, rv1);

    // zero pooled-sum accumulator (after lin1's last agg7 read)
    k_zero_pool<<<4096, 256, 0, stream>>>();

    // layers 2,3: fused gather + MFMA GEMM
    // layer2: hin=g_hA fp8 (q1) -> hout=g_hB fp8 (h2)
    // layer3: hin=g_hB fp8 (h2) -> fused pooling atomics (no h3)
    k_agg_gemm<true,  true,  0, 1><<<N_NODES / 64, 256, 0, stream>>>(b2, g2, bt2, rm2, rv2, batch);
    k_agg_gemm<false, false, 1, 2><<<N_NODES / 64, 256, 0, stream>>>(b3, g3, bt3, rm3, rv3, batch);

    // head MLP (head1 divides pooled sums by counts)
    k_head1<<<(N_GRAPHS * 64) / 256, 256, 0, stream>>>(Wc1, bc1);
    k_head2<<<(N_GRAPHS + 255) / 256, 256, 0, stream>>>(Wc2, bc2, outp);
}

// Round 6
// 1117.504 us; speedup vs baseline: 4.0654x; 1.0684x over previous
//
#include <hip/hip_runtime.h>
#include <hip/hip_fp16.h>

#define N_NODES 1000000
#define N_EDGES 4000000
#define N_GRAPHS 32768
#define BN_EPS 1e-5f
#define NBLK1 3907   // ceil(N_NODES/256)

typedef _Float16 f16;
typedef f16   f16x8 __attribute__((ext_vector_type(8)));
typedef float f32x4 __attribute__((ext_vector_type(4)));
typedef float f32x2 __attribute__((ext_vector_type(2)));

// ---------------------------------------------------------------------------
// Static device-global scratch.
// r21: gather-read features fp8 e4m3 (q1, h2). r22: h3 never materialized
// (fused pooling). r23: layer-1 fully fused (px fp16x8 -> gather -> MFMA
// lin1 -> fp8 q1); agg7 intermediate deleted.
// ---------------------------------------------------------------------------
__device__ __half g_hA[128000000];      // 256 MB: q1 fp8 (first 128 MB)
__device__ __half g_hB[128000000];      // 256 MB: px fp16x8 (16 MB) -> h2 fp8 (128 MB)
__device__ float  g_agg7[8400000];      //  33.6 MB: pooled SUMS + hidden
__device__ float  g_dinv[N_NODES];
__device__ int    g_rowcnt[N_NODES];
__device__ int    g_row_start[N_NODES + 1];
__device__ int    g_csr_src[N_EDGES];
__device__ int    g_part[NBLK1];
__device__ int    g_gstart[N_GRAPHS + 1];
__device__ __align__(16) __half g_wt1[4096];    // W1^T fp16 [n][k], K padded to 32
__device__ __align__(16) __half g_wt2[16384];   // W2^T fp16 [n][k]
__device__ __align__(16) __half g_wt3[16384];   // W3^T fp16 [n][k]

#define HIDDEN_OFF 4259840   // pooled sums = g_agg7[0..4194304); hidden after pad

// ---------------- fp16 helpers ----------------

__device__ __forceinline__ void set8(uint4 raw, float f[8]) {
    __half2 h; float2 a;
    __builtin_memcpy(&h, &raw.x, 4); a = __half22float2(h); f[0] = a.x; f[1] = a.y;
    __builtin_memcpy(&h, &raw.y, 4); a = __half22float2(h); f[2] = a.x; f[3] = a.y;
    __builtin_memcpy(&h, &raw.z, 4); a = __half22float2(h); f[4] = a.x; f[5] = a.y;
    __builtin_memcpy(&h, &raw.w, 4); a = __half22float2(h); f[6] = a.x; f[7] = a.y;
}
__device__ __forceinline__ uint4 pack8(const float f[8]) {
    __half2 h0 = __floats2half2_rn(f[0], f[1]);
    __half2 h1 = __floats2half2_rn(f[2], f[3]);
    __half2 h2 = __floats2half2_rn(f[4], f[5]);
    __half2 h3 = __floats2half2_rn(f[6], f[7]);
    uint4 raw;
    __builtin_memcpy(&raw.x, &h0, 4);
    __builtin_memcpy(&raw.y, &h1, 4);
    __builtin_memcpy(&raw.z, &h2, 4);
    __builtin_memcpy(&raw.w, &h3, 4);
    return raw;
}
__device__ __forceinline__ f32x2 cvt2h(unsigned raw) {
    __half2 h; __builtin_memcpy(&h, &raw, 4);
    float2 a = __half22float2(h);
    f32x2 r; r.x = a.x; r.y = a.y; return r;
}

// ---------------- fp8 e4m3 helpers (vector f32x2 accumulators) ----------------

__device__ __forceinline__ void set8_fp8v(uint2 raw, f32x2 f[4]) {
    f[0] = __builtin_amdgcn_cvt_pk_f32_fp8(raw.x, false);
    f[1] = __builtin_amdgcn_cvt_pk_f32_fp8(raw.x, true);
    f[2] = __builtin_amdgcn_cvt_pk_f32_fp8(raw.y, false);
    f[3] = __builtin_amdgcn_cvt_pk_f32_fp8(raw.y, true);
}
__device__ __forceinline__ void add8_fp8v(uint2 raw, f32x2 f[4]) {
    f[0] += __builtin_amdgcn_cvt_pk_f32_fp8(raw.x, false);   // v_pk_add_f32
    f[1] += __builtin_amdgcn_cvt_pk_f32_fp8(raw.x, true);
    f[2] += __builtin_amdgcn_cvt_pk_f32_fp8(raw.y, false);
    f[3] += __builtin_amdgcn_cvt_pk_f32_fp8(raw.y, true);
}
__device__ __forceinline__ uint4 pack8v(const f32x2 f[4]) {
    __half2 h0 = __floats2half2_rn(f[0].x, f[0].y);
    __half2 h1 = __floats2half2_rn(f[1].x, f[1].y);
    __half2 h2 = __floats2half2_rn(f[2].x, f[2].y);
    __half2 h3 = __floats2half2_rn(f[3].x, f[3].y);
    uint4 raw;
    __builtin_memcpy(&raw.x, &h0, 4);
    __builtin_memcpy(&raw.y, &h1, 4);
    __builtin_memcpy(&raw.z, &h2, 4);
    __builtin_memcpy(&raw.w, &h3, 4);
    return raw;
}
__device__ __forceinline__ uint2 pack8_fp8(const float f[8]) {
    int lo = 0, hi = 0;
    lo = __builtin_amdgcn_cvt_pk_fp8_f32(f[0], f[1], lo, false);
    lo = __builtin_amdgcn_cvt_pk_fp8_f32(f[2], f[3], lo, true);
    hi = __builtin_amdgcn_cvt_pk_fp8_f32(f[4], f[5], hi, false);
    hi = __builtin_amdgcn_cvt_pk_fp8_f32(f[6], f[7], hi, true);
    uint2 r; r.x = (unsigned)lo; r.y = (unsigned)hi; return r;
}

// ---------------- CSR build ----------------

__global__ __launch_bounds__(256) void k_zero_cnt() {
    int i = blockIdx.x * 256 + threadIdx.x;
    if (i < N_NODES) g_rowcnt[i] = 0;
}

__global__ __launch_bounds__(256) void k_hist(const int* __restrict__ dst) {
    int e = blockIdx.x * 256 + threadIdx.x;
    if (e < N_EDGES) atomicAdd(&g_rowcnt[dst[e]], 1);
}

__global__ __launch_bounds__(256) void k_scan1() {
    __shared__ int sh[256];
    int i = blockIdx.x * 256 + threadIdx.x;
    int v = (i < N_NODES) ? g_rowcnt[i] : 0;
    if (i < N_NODES) g_dinv[i] = rsqrtf((float)(1 + v));   // +1 self-loop
    sh[threadIdx.x] = v;
    __syncthreads();
#pragma unroll
    for (int off = 1; off < 256; off <<= 1) {
        int t = (threadIdx.x >= off) ? sh[threadIdx.x - off] : 0;
        __syncthreads();
        sh[threadIdx.x] += t;
        __syncthreads();
    }
    int incl = sh[threadIdx.x];
    if (i < N_NODES) g_row_start[i] = incl - v;
    if (threadIdx.x == 255) g_part[blockIdx.x] = incl;
}

__global__ __launch_bounds__(256) void k_scan2() {
    __shared__ int sh[256];
    int base = threadIdx.x * 16;
    int local[16];
    int s = 0;
#pragma unroll
    for (int k = 0; k < 16; ++k) {
        local[k] = (base + k < NBLK1) ? g_part[base + k] : 0;
        s += local[k];
    }
    sh[threadIdx.x] = s;
    __syncthreads();
#pragma unroll
    for (int off = 1; off < 256; off <<= 1) {
        int t = (threadIdx.x >= off) ? sh[threadIdx.x - off] : 0;
        __syncthreads();
        sh[threadIdx.x] += t;
        __syncthreads();
    }
    int carry = sh[threadIdx.x] - s;
#pragma unroll
    for (int k = 0; k < 16; ++k) {
        if (base + k < NBLK1) {
            int t = local[k];
            g_part[base + k] = carry;
            carry += t;
        }
    }
}

__global__ __launch_bounds__(256) void k_scan3() {
    int i = blockIdx.x * 256 + threadIdx.x;
    if (i < N_NODES) {
        g_row_start[i] += g_part[blockIdx.x];
        g_rowcnt[i] = 0;
    }
    if (i == 0) g_row_start[N_NODES] = N_EDGES;
}

__global__ __launch_bounds__(256) void k_scatter(const int* __restrict__ src,
                                                 const int* __restrict__ dst) {
    int e = blockIdx.x * 256 + threadIdx.x;
    if (e >= N_EDGES) return;
    int d = dst[e];
    int pos = g_row_start[d] + atomicAdd(&g_rowcnt[d], 1);
    g_csr_src[pos] = src[e];
}

// ---------------- weight transposes to fp16 ----------------

__global__ __launch_bounds__(256) void k_wt_both(const float* __restrict__ W2,
                                                 const float* __restrict__ W3) {
    int t = blockIdx.x * 256 + threadIdx.x;   // 0..32767
    int sel = t >> 14, u = t & 16383;
    int n = u & 127, k = u >> 7;
    __half* dst = sel ? g_wt3 : g_wt2;
    const float* W = sel ? W3 : W2;
    dst[n * 128 + k] = __float2half_rn(W[k * 128 + n]);
}

// W1^T fp16 [128][32], rows k>=7 zero (K padded for 16x16x32 MFMA)
__global__ __launch_bounds__(256) void k_wt1(const float* __restrict__ W1) {
    int t = blockIdx.x * 256 + threadIdx.x;   // 0..4095
    int n = t & 127, k = t >> 7;              // k 0..31
    g_wt1[n * 32 + k] = (k < 7) ? __float2half_rn(W1[k * 128 + n]) : __float2half_rn(0.f);
}

// ---------------- layer 1 ----------------

// px[i] = fp16x8 padded row of dinv[i]*x[i] (16 B); ch7 = 0.
__global__ __launch_bounds__(256) void k_p7(const float* __restrict__ x) {
    int i = blockIdx.x * 256 + threadIdx.x;
    if (i >= N_NODES) return;
    float w = g_dinv[i];
    float v[8];
#pragma unroll
    for (int k = 0; k < 7; ++k) v[k] = x[i * 7 + k] * w;
    v[7] = 0.f;
    *(uint4*)(g_hB + (size_t)i * 8) = pack8(v);
}

// zero the pooled-sum accumulator (16.78 MB) before layer-3's atomics
__global__ __launch_bounds__(256) void k_zero_pool() {
    int t = blockIdx.x * 256 + threadIdx.x;          // 0..1048575
    *(float4*)(g_agg7 + (size_t)t * 4) = make_float4(0.f, 0.f, 0.f, 0.f);
}

// ---------------- fused layer-1: gather(px) + MFMA lin1 + BN/ReLU -> q1 fp8
// r23: replaces k_agg7_csr + k_lin1 (and deletes the 64 MB agg7 round trip;
// the old pair was part of an invisible ~740 us non-GEMM bucket).
// 64 nodes/block, 256 threads. Gather: 4 threads/node (q = tid&3 handles
// channels 2q,2q+1 via ONE 4 B load/edge); f32x2 accumulate (v_pk_add_f32);
// stage As[64][0..7] = agg fp16, halves 8..39 zeroed -> K=32 MFMA vs g_wt1.
// Epilogue = verified layer-2 PRE epilogue (y = relu((z*dv)*s+o)*dv), fp8.

__global__ __launch_bounds__(256, 7) void k_l1_fused(const float* __restrict__ b,
                                                     const float* __restrict__ g,
                                                     const float* __restrict__ bt,
                                                     const float* __restrict__ rm,
                                                     const float* __restrict__ rv) {
    const __half* __restrict__ px = g_hB;
    unsigned char* __restrict__ q1 = (unsigned char*)g_hA;

    __shared__ __half As[64][152];          // 19,456 B (gather uses cols 0..39; C staging reuses all)
    const int tid = threadIdx.x;
    const int node0 = blockIdx.x * 64;

    // ---- gather: 4 threads/node, one pass ----
    {
        const int slot = tid >> 2;          // 0..63
        const int q = tid & 3;              // channel pair
        int i = node0 + slot;
        f32x2 f = cvt2h(*(const unsigned*)(px + (size_t)i * 8 + q * 2));   // self
        int e = g_row_start[i], e1 = g_row_start[i + 1];
        for (; e + 4 <= e1; e += 4) {
            int s0 = g_csr_src[e + 0], s1 = g_csr_src[e + 1];
            int s2 = g_csr_src[e + 2], s3 = g_csr_src[e + 3];
            unsigned r0 = *(const unsigned*)(px + (size_t)s0 * 8 + q * 2);
            unsigned r1 = *(const unsigned*)(px + (size_t)s1 * 8 + q * 2);
            unsigned r2 = *(const unsigned*)(px + (size_t)s2 * 8 + q * 2);
            unsigned r3 = *(const unsigned*)(px + (size_t)s3 * 8 + q * 2);
            f += cvt2h(r0); f += cvt2h(r1); f += cvt2h(r2); f += cvt2h(r3);
        }
        for (; e < e1; ++e)
            f += cvt2h(*(const unsigned*)(px + (size_t)g_csr_src[e] * 8 + q * 2));
        __half2 hv = __floats2half2_rn(f.x, f.y);
        unsigned u; __builtin_memcpy(&u, &hv, 4);
        *(unsigned*)(&As[slot][q * 2]) = u;
        uint4 z; z.x = 0; z.y = 0; z.z = 0; z.w = 0;
        *(uint4*)(&As[slot][8 + q * 8]) = z;    // zero K pad halves 8..39
    }

    const int wv = tid >> 6;        // wave 0..3 -> cols [wv*32, wv*32+32)
    const int lane = tid & 63;
    const int lm = lane & 15;
    const int lq = lane >> 4;

    __syncthreads();

    // ---- MFMA: K=32 (single kb) ----
    f32x4 acc[4][2];
#pragma unroll
    for (int mt = 0; mt < 4; ++mt)
#pragma unroll
        for (int nt = 0; nt < 2; ++nt) acc[mt][nt] = (f32x4){0.f, 0.f, 0.f, 0.f};

    f16x8 bq[2];
#pragma unroll
    for (int nt = 0; nt < 2; ++nt)
        __builtin_memcpy(&bq[nt], g_wt1 + (size_t)(wv * 32 + nt * 16 + lm) * 32 + lq * 8, 16);
#pragma unroll
    for (int mt = 0; mt < 4; ++mt) {
        f16x8 afr;
        __builtin_memcpy(&afr, &As[mt * 16 + lm][lq * 8], 16);
#pragma unroll
        for (int nt = 0; nt < 2; ++nt)
            acc[mt][nt] = __builtin_amdgcn_mfma_f32_16x16x32_f16(afr, bq[nt], acc[mt][nt], 0, 0, 0);
    }

    float4 dv4[4];
#pragma unroll
    for (int mt = 0; mt < 4; ++mt)
        dv4[mt] = *(const float4*)(g_dinv + node0 + mt * 16 + lq * 4);

    __syncthreads();   // all As gather reads done before C staging

    // ---- epilogue: BN/ReLU (PRE), stage C fp16 in As ----
#pragma unroll
    for (int nt = 0; nt < 2; ++nt) {
        int c = wv * 32 + nt * 16 + lm;
        float s = g[c] * rsqrtf(rv[c] + BN_EPS);
        float o = fmaf(b[c] - rm[c], s, bt[c]);
#pragma unroll
        for (int mt = 0; mt < 4; ++mt) {
            float dvr[4] = {dv4[mt].x, dv4[mt].y, dv4[mt].z, dv4[mt].w};
#pragma unroll
            for (int r = 0; r < 4; ++r) {
                float y = fmaxf(fmaf(acc[mt][nt][r] * dvr[r], s, o), 0.f) * dvr[r];
                As[mt * 16 + lq * 4 + r][c] = __float2half_rn(y);
            }
        }
    }
    __syncthreads();
#pragma unroll
    for (int i = 0; i < 2; ++i) {
        int u = tid + i * 256;                 // 0..511
        int row = u >> 3, cb = (u & 7) * 16;   // 16 cols/thread
        float fa[8], fb[8];
        set8(*(const uint4*)(&As[row][cb]), fa);
        set8(*(const uint4*)(&As[row][cb + 8]), fb);
        uint2 pa = pack8_fp8(fa), pb = pack8_fp8(fb);
        uint4 v; v.x = pa.x; v.y = pa.y; v.z = pb.x; v.w = pb.y;
        *(uint4*)(q1 + (size_t)(node0 + row) * 128 + cb) = v;
    }
}

// ---------------- fused CSR-gather + MFMA GEMM + BN + ReLU (layers 2,3) ----
// LEDGER:
//  r18 interleaved gather -> reg spills. REVERTED (sequential 4-pass).
//  r19 nt stores -> partial-line HBM writes. REVERTED.
//  r19b launch_bounds(256,8) -> scratch thrash. Now (256,7).
//  r20 occupancy 55->79%, dur flat => HBM-traffic-bound. Lever = bytes.
//  r21 fp8 rows: 374 -> 277 us. r22 fused pooling: 277 -> 237 us; now no
//      pipe saturated (HBM 19%, VALU 36%) — likely at the random-128B-row
//      combined L3+HBM service ceiling (~2.7 TB/s demand).
//  r23 f32x2 pk-add accumulate (minor VALU cut).
// OUTMODE: 1 = fp8 row store (layer 2), 2 = fused pool (layer 3).

template <bool PRE, bool ATOB, int WSEL, int OUTMODE>
__global__ __launch_bounds__(256, 7) void k_agg_gemm(const float* __restrict__ b,
                                                     const float* __restrict__ g,
                                                     const float* __restrict__ bt,
                                                     const float* __restrict__ rm,
                                                     const float* __restrict__ rv,
                                                     const int* __restrict__ batch) {
    const unsigned char* __restrict__ hin8 =
        (const unsigned char*)(ATOB ? g_hA : g_hB);          // fp8 rows, 128 B
    unsigned char* __restrict__ hout8 =
        (unsigned char*)(ATOB ? g_hB : g_hA);                // fp8 rows, 128 B
    const __half* __restrict__ WtG = (WSEL == 0) ? g_wt2 : g_wt3;

    __shared__ __half As[64][152];          // 19,456 B
    __shared__ int bsh[64];
    const int tid = threadIdx.x;
    const int node0 = blockIdx.x * 64;

    // ---- gather phase (sequential 4-pass; fp8 rows, f32x2 accumulate) ----
    {
        const int slot = tid >> 4;          // 0..15
        const int c0 = (tid & 15) * 8;      // 8 channels = 8 fp8 bytes
#pragma unroll
        for (int pass = 0; pass < 4; ++pass) {
            int i = node0 + pass * 16 + slot;
            f32x2 f[4];
            set8_fp8v(*(const uint2*)(hin8 + (size_t)i * 128 + c0), f);   // self
            int e = g_row_start[i], e1 = g_row_start[i + 1];
            for (; e + 4 <= e1; e += 4) {
                int s0 = g_csr_src[e + 0], s1 = g_csr_src[e + 1];
                int s2 = g_csr_src[e + 2], s3 = g_csr_src[e + 3];
                uint2 r0 = *(const uint2*)(hin8 + (size_t)s0 * 128 + c0);
                uint2 r1 = *(const uint2*)(hin8 + (size_t)s1 * 128 + c0);
                uint2 r2 = *(const uint2*)(hin8 + (size_t)s2 * 128 + c0);
                uint2 r3 = *(const uint2*)(hin8 + (size_t)s3 * 128 + c0);
                add8_fp8v(r0, f); add8_fp8v(r1, f); add8_fp8v(r2, f); add8_fp8v(r3, f);
            }
            for (; e < e1; ++e) {
                int s = g_csr_src[e];
                add8_fp8v(*(const uint2*)(hin8 + (size_t)s * 128 + c0), f);
            }
            int row = pass * 16 + slot;
            *(uint4*)(&As[row][c0]) = pack8v(f);
        }
    }

    const int wv = tid >> 6;        // wave 0..3 -> cols [wv*32, wv*32+32)
    const int lane = tid & 63;
    const int lm = lane & 15;
    const int lq = lane >> 4;

    __syncthreads();

    // ---- MFMA: kb-outer so only 2 B-frags live at a time ----
    f32x4 acc[4][2];
#pragma unroll
    for (int mt = 0; mt < 4; ++mt)
#pragma unroll
        for (int nt = 0; nt < 2; ++nt) acc[mt][nt] = (f32x4){0.f, 0.f, 0.f, 0.f};

#pragma unroll
    for (int kb = 0; kb < 4; ++kb) {
        f16x8 bq[2];
#pragma unroll
        for (int nt = 0; nt < 2; ++nt)
            __builtin_memcpy(&bq[nt],
                             WtG + (size_t)(wv * 32 + nt * 16 + lm) * 128 + kb * 32 + lq * 8, 16);
#pragma unroll
        for (int mt = 0; mt < 4; ++mt) {
            f16x8 afr;
            __builtin_memcpy(&afr, &As[mt * 16 + lm][kb * 32 + lq * 8], 16);
#pragma unroll
            for (int nt = 0; nt < 2; ++nt)
                acc[mt][nt] = __builtin_amdgcn_mfma_f32_16x16x32_f16(afr, bq[nt], acc[mt][nt], 0, 0, 0);
        }
    }

    float4 dv4[4];
#pragma unroll
    for (int mt = 0; mt < 4; ++mt)
        dv4[mt] = *(const float4*)(g_dinv + node0 + mt * 16 + lq * 4);

    if (OUTMODE == 2 && tid < 64) bsh[tid] = batch[node0 + tid];

    __syncthreads();

    // ---- epilogue: BN/ReLU, stage C (fp16) in As ----
#pragma unroll
    for (int nt = 0; nt < 2; ++nt) {
        int c = wv * 32 + nt * 16 + lm;
        float s = g[c] * rsqrtf(rv[c] + BN_EPS);
        float o = fmaf(b[c] - rm[c], s, bt[c]);
#pragma unroll
        for (int mt = 0; mt < 4; ++mt) {
            float dvr[4] = {dv4[mt].x, dv4[mt].y, dv4[mt].z, dv4[mt].w};
#pragma unroll
            for (int r = 0; r < 4; ++r) {
                float pm = PRE ? dvr[r] : 1.0f;
                float y = fmaxf(fmaf(acc[mt][nt][r] * dvr[r], s, o), 0.f) * pm;
                As[mt * 16 + lq * 4 + r][c] = __float2half_rn(y);
            }
        }
    }
    __syncthreads();

    if (OUTMODE == 1) {
#pragma unroll
        for (int i = 0; i < 2; ++i) {
            int u = tid + i * 256;                 // 0..511
            int row = u >> 3, cb = (u & 7) * 16;   // 16 cols/thread
            float fa[8], fb[8];
            set8(*(const uint4*)(&As[row][cb]), fa);
            set8(*(const uint4*)(&As[row][cb + 8]), fb);
            uint2 pa = pack8_fp8(fa), pb = pack8_fp8(fb);
            uint4 v; v.x = pa.x; v.y = pa.y; v.z = pb.x; v.w = pb.y;
            *(uint4*)(hout8 + (size_t)(node0 + row) * 128 + cb) = v;
        }
    } else {
        // fused segment-sum pooling (batch sorted): run-length sum by graph.
        const int c = tid & 127;
        const int r0 = (tid >> 7) * 32;
        float accp = 0.f;
        int g0 = bsh[r0];
        for (int row = r0; row < r0 + 32; ++row) {
            int gg = bsh[row];
            if (gg != g0) {
                atomicAdd(&g_agg7[(size_t)g0 * 128 + c], accp);
                accp = 0.f; g0 = gg;
            }
            accp += __half2float(As[row][c]);
        }
        atomicAdd(&g_agg7[(size_t)g0 * 128 + c], accp);
    }
}

// ---------------- pooling boundaries + head ----------------

__global__ __launch_bounds__(256) void k_gstart(const int* __restrict__ batch) {
    int gidx = blockIdx.x * 256 + threadIdx.x;
    if (gidx > N_GRAPHS) return;
    int lo = 0, hi = N_NODES;
    while (lo < hi) {
        int mid = (lo + hi) >> 1;
        if (batch[mid] < gidx) lo = mid + 1; else hi = mid;
    }
    g_gstart[gidx] = lo;
}

// hidden = relu((pooled_sum/cnt) @ Wc1 + bc1)
__global__ __launch_bounds__(256) void k_head1(const float* __restrict__ Wc1,
                                               const float* __restrict__ bc1) {
    int t = blockIdx.x * 256 + threadIdx.x;
    int gi = t >> 6, c = t & 63;
    if (gi >= N_GRAPHS) return;
    const float* pooled = g_agg7;
    float* hidden = g_agg7 + HIDDEN_OFF;
    int cnt = g_gstart[gi + 1] - g_gstart[gi];
    float inv = 1.0f / (float)max(cnt, 1);
    float z = 0.f;
#pragma unroll 8
    for (int k = 0; k < 128; ++k) z = fmaf(pooled[gi * 128 + k], Wc1[k * 64 + c], z);
    hidden[t] = fmaxf(fmaf(z, inv, bc1[c]), 0.f);
}

__global__ __launch_bounds__(256) void k_head2(const float* __restrict__ Wc2,
                                               const float* __restrict__ bc2,
                                               float* __restrict__ out) {
    int gi = blockIdx.x * 256 + threadIdx.x;
    if (gi >= N_GRAPHS) return;
    const float* hidden = g_agg7 + HIDDEN_OFF;
    float z = bc2[0];
#pragma unroll 8
    for (int k = 0; k < 64; ++k) z = fmaf(hidden[gi * 64 + k], Wc2[k], z);
    out[gi] = z;
}

// ---------------- launch ----------------

extern "C" void kernel_launch(void* const* d_in, const int* in_sizes, int n_in,
                              void* d_out, int out_size, void* d_ws, size_t ws_size,
                              hipStream_t stream) {
    const float* x     = (const float*)d_in[0];
    const int*   ei    = (const int*)d_in[1];
    const int*   batch = (const int*)d_in[2];
    const float* W1 = (const float*)d_in[3];
    const float* b1 = (const float*)d_in[4];
    const float* g1 = (const float*)d_in[5];
    const float* bt1= (const float*)d_in[6];
    const float* rm1= (const float*)d_in[7];
    const float* rv1= (const float*)d_in[8];
    const float* W2 = (const float*)d_in[9];
    const float* b2 = (const float*)d_in[10];
    const float* g2 = (const float*)d_in[11];
    const float* bt2= (const float*)d_in[12];
    const float* rm2= (const float*)d_in[13];
    const float* rv2= (const float*)d_in[14];
    const float* W3 = (const float*)d_in[15];
    const float* b3 = (const float*)d_in[16];
    const float* g3 = (const float*)d_in[17];
    const float* bt3= (const float*)d_in[18];
    const float* rm3= (const float*)d_in[19];
    const float* rv3= (const float*)d_in[20];
    const float* Wc1= (const float*)d_in[21];
    const float* bc1= (const float*)d_in[22];
    const float* Wc2= (const float*)d_in[23];
    const float* bc2= (const float*)d_in[24];
    float* outp = (float*)d_out;
    (void)d_ws; (void)ws_size; (void)n_in; (void)in_sizes;

    const int* srcp = ei;
    const int* dstp = ei + N_EDGES;

    // CSR build (by dst) + dinv (fused into scan1)
    k_zero_cnt<<<NBLK1, 256, 0, stream>>>();
    k_hist<<<(N_EDGES + 255) / 256, 256, 0, stream>>>(dstp);
    k_scan1<<<NBLK1, 256, 0, stream>>>();
    k_scan2<<<1, 256, 0, stream>>>();
    k_scan3<<<NBLK1, 256, 0, stream>>>();
    k_scatter<<<(N_EDGES + 255) / 256, 256, 0, stream>>>(srcp, dstp);

    // weight transposes -> fp16
    k_wt_both<<<128, 256, 0, stream>>>(W2, W3);
    k_wt1<<<16, 256, 0, stream>>>(W1);

    // graph boundaries + pooled-sum zeroing
    k_gstart<<<(N_GRAPHS + 1 + 255) / 256, 256, 0, stream>>>(batch);
    k_zero_pool<<<4096, 256, 0, stream>>>();

    // layer 1: px fp16x8 -> fused gather+MFMA lin1+BN/ReLU -> q1 fp8
    k_p7<<<(N_NODES + 255) / 256, 256, 0, stream>>>(x);
    k_l1_fused<<<N_NODES / 64, 256, 0, stream>>>(b1, g1, bt1, rm1, rv1);

    // layers 2,3: fused gather + MFMA GEMM
    k_agg_gemm<true,  true,  0, 1><<<N_NODES / 64, 256, 0, stream>>>(b2, g2, bt2, rm2, rv2, batch);
    k_agg_gemm<false, false, 1, 2><<<N_NODES / 64, 256, 0, stream>>>(b3, g3, bt3, rm3, rv3, batch);

    // head MLP
    k_head1<<<(N_GRAPHS * 64) / 256, 256, 0, stream>>>(Wc1, bc1);
    k_head2<<<(N_GRAPHS + 255) / 256, 256, 0, stream>>>(Wc2, bc2, outp);
}